// Round 1
// baseline (2439.547 us; speedup 1.0000x reference)
//
#include <hip/hip_runtime.h>
#include <math.h>

// Problem constants
#define NSEQ 2048
#define DDIM 1024
#define BSZ  4

// GEMM tiling
#define TS 64          // output tile (M and N)
#define KC 16          // k-chunk
#define LP 68          // padded LDS row stride (64 + 4, keeps float4 alignment)

// ---------------------------------------------------------------------------
// Shared tile-GEMM bodies. Both compute a 64x64 output tile with a 256-thread
// block, 4x4 microtile per thread, accumulators in registers.
// gemm_bt: C = A[M,K] (row-major) * Bt[N,K]^T (row-major "B-transposed" input)
// gemm_ab: C = A[M,K] (row-major) * B[K,N]  (row-major)
// ---------------------------------------------------------------------------

__device__ __forceinline__ void gemm_bt_body(
    const float* __restrict__ A, const float* __restrict__ Bt,
    int lda, int ldb, int K, int row0, int col0,
    float* As, float* Bs, float acc[4][4])
{
  const int tid = threadIdx.x;
  const int lm = tid >> 2;          // 0..63 tile row for loading
  const int lk = (tid & 3) << 2;    // 0,4,8,12 k offset (float4)
  const int cm = (tid >> 4) << 2;   // microtile row base
  const int cn = (tid & 15) << 2;   // microtile col base

  const float* Aptr = A + (size_t)(row0 + lm) * lda + lk;
  const float* Bptr = Bt + (size_t)(col0 + lm) * ldb + lk;

  for (int k0 = 0; k0 < K; k0 += KC) {
    float4 a4 = *(const float4*)(Aptr + k0);
    float4 b4 = *(const float4*)(Bptr + k0);
    As[(lk + 0) * LP + lm] = a4.x;
    As[(lk + 1) * LP + lm] = a4.y;
    As[(lk + 2) * LP + lm] = a4.z;
    As[(lk + 3) * LP + lm] = a4.w;
    Bs[(lk + 0) * LP + lm] = b4.x;
    Bs[(lk + 1) * LP + lm] = b4.y;
    Bs[(lk + 2) * LP + lm] = b4.z;
    Bs[(lk + 3) * LP + lm] = b4.w;
    __syncthreads();
#pragma unroll
    for (int kk = 0; kk < KC; ++kk) {
      const float4 av = *(const float4*)(As + kk * LP + cm);
      const float4 bv = *(const float4*)(Bs + kk * LP + cn);
      const float a[4] = {av.x, av.y, av.z, av.w};
      const float b[4] = {bv.x, bv.y, bv.z, bv.w};
#pragma unroll
      for (int i = 0; i < 4; ++i)
#pragma unroll
        for (int j = 0; j < 4; ++j)
          acc[i][j] = fmaf(a[i], b[j], acc[i][j]);
    }
    __syncthreads();
  }
}

__device__ __forceinline__ void gemm_ab_body(
    const float* __restrict__ A, const float* __restrict__ B,
    int lda, int ldb, int K, int row0, int col0,
    float* As, float* Bs, float acc[4][4])
{
  const int tid = threadIdx.x;
  const int lm = tid >> 2;
  const int lk = (tid & 3) << 2;
  const int bk = tid >> 4;          // 0..15 k row of B tile
  const int bn = (tid & 15) << 2;   // col offset (float4)
  const int cm = (tid >> 4) << 2;
  const int cn = (tid & 15) << 2;

  const float* Aptr = A + (size_t)(row0 + lm) * lda + lk;
  const float* Bptr = B + (size_t)bk * ldb + col0 + bn;

  for (int k0 = 0; k0 < K; k0 += KC) {
    float4 a4 = *(const float4*)(Aptr + k0);
    float4 b4 = *(const float4*)(Bptr + (size_t)k0 * ldb);
    As[(lk + 0) * LP + lm] = a4.x;
    As[(lk + 1) * LP + lm] = a4.y;
    As[(lk + 2) * LP + lm] = a4.z;
    As[(lk + 3) * LP + lm] = a4.w;
    *(float4*)(Bs + bk * LP + bn) = b4;
    __syncthreads();
#pragma unroll
    for (int kk = 0; kk < KC; ++kk) {
      const float4 av = *(const float4*)(As + kk * LP + cm);
      const float4 bv = *(const float4*)(Bs + kk * LP + cn);
      const float a[4] = {av.x, av.y, av.z, av.w};
      const float b[4] = {bv.x, bv.y, bv.z, bv.w};
#pragma unroll
      for (int i = 0; i < 4; ++i)
#pragma unroll
        for (int j = 0; j < 4; ++j)
          acc[i][j] = fmaf(a[i], b[j], acc[i][j]);
    }
    __syncthreads();
  }
}

__device__ __forceinline__ float sigmoidf_(float x) {
  return 1.0f / (1.0f + expf(-x));
}

// ---------------------------------------------------------------------------
// 1) QKV: q/k/v = x @ W{q,k,v}^T   (x: [8192,1024], W: [1024,1024])
// ---------------------------------------------------------------------------
__global__ __launch_bounds__(256) void k_qkv(
    const float* __restrict__ x,
    const float* __restrict__ Wq, const float* __restrict__ Wk,
    const float* __restrict__ Wv,
    float* __restrict__ q, float* __restrict__ k, float* __restrict__ v)
{
  __shared__ float As[KC * LP];
  __shared__ float Bs[KC * LP];
  const int z = blockIdx.z;
  const float* W = (z == 0) ? Wq : ((z == 1) ? Wk : Wv);
  float* O = (z == 0) ? q : ((z == 1) ? k : v);
  const int row0 = blockIdx.x * TS;
  const int col0 = blockIdx.y * TS;
  float acc[4][4] = {};
  gemm_bt_body(x, W, DDIM, DDIM, DDIM, row0, col0, As, Bs, acc);
  const int cm = (threadIdx.x >> 4) << 2;
  const int cn = (threadIdx.x & 15) << 2;
#pragma unroll
  for (int i = 0; i < 4; ++i) {
    float4 r = make_float4(acc[i][0], acc[i][1], acc[i][2], acc[i][3]);
    *(float4*)(O + (size_t)(row0 + cm + i) * DDIM + col0 + cn) = r;
  }
}

// ---------------------------------------------------------------------------
// 2) Scores: att[b,i,j] = (q_i . k_j)/32 + rel_bias[i,j], causal-masked.
//    Only tiles with j-tile <= i-tile are computed.
// ---------------------------------------------------------------------------
__global__ __launch_bounds__(256) void k_scores(
    const float* __restrict__ q, const float* __restrict__ k,
    const float* __restrict__ rb, float* __restrict__ att)
{
  const int it = blockIdx.x, jt = blockIdx.y, b = blockIdx.z;
  if (jt > it) return;
  __shared__ float As[KC * LP];
  __shared__ float Bs[KC * LP];
  const int row0 = it * TS;
  const int col0 = jt * TS;
  const float* A = q + (size_t)b * NSEQ * DDIM;
  const float* Bt = k + (size_t)b * NSEQ * DDIM;
  float acc[4][4] = {};
  gemm_bt_body(A, Bt, DDIM, DDIM, DDIM, row0, col0, As, Bs, acc);
  const int cm = (threadIdx.x >> 4) << 2;
  const int cn = (threadIdx.x & 15) << 2;
  const float scale = 0.03125f;  // 1/sqrt(1024)
  float* abase = att + (size_t)b * NSEQ * NSEQ;
#pragma unroll
  for (int ii = 0; ii < 4; ++ii) {
    const int i = row0 + cm + ii;
    const float* brow = rb + (size_t)i * NSEQ;
    float* arow = abase + (size_t)i * NSEQ;
#pragma unroll
    for (int jj = 0; jj < 4; ++jj) {
      const int j = col0 + cn + jj;
      float val = acc[ii][jj] * scale + brow[j];
      arow[j] = (j <= i) ? val : -1e30f;
    }
  }
}

// ---------------------------------------------------------------------------
// 3) Row softmax (causal). Writes probs for j<=i and zeros up to the end of
//    the diagonal 64-tile so the PV GEMM can read whole tiles.
// ---------------------------------------------------------------------------
__global__ __launch_bounds__(256) void k_softmax(float* __restrict__ att)
{
  const int i = blockIdx.x, b = blockIdx.y;
  float* row = att + ((size_t)b * NSEQ + i) * NSEQ;
  const int valid = i + 1;
  const int wlen = ((i >> 6) + 1) << 6;
  const int tid = threadIdx.x;
  const int lane = tid & 63, wid = tid >> 6;

  float v[8];
  float m = -1e30f;
#pragma unroll
  for (int t = 0; t < 8; ++t) {
    const int idx = tid + (t << 8);
    v[t] = (idx < valid) ? row[idx] : -1e30f;
    m = fmaxf(m, v[t]);
  }
#pragma unroll
  for (int off = 32; off; off >>= 1) m = fmaxf(m, __shfl_xor(m, off));
  __shared__ float red[4];
  if (lane == 0) red[wid] = m;
  __syncthreads();
  m = fmaxf(fmaxf(red[0], red[1]), fmaxf(red[2], red[3]));
  __syncthreads();

  float s = 0.f;
#pragma unroll
  for (int t = 0; t < 8; ++t) {
    const int idx = tid + (t << 8);
    float e = (idx < valid) ? expf(v[t] - m) : 0.f;
    v[t] = e;
    s += e;
  }
#pragma unroll
  for (int off = 32; off; off >>= 1) s += __shfl_xor(s, off);
  if (lane == 0) red[wid] = s;
  __syncthreads();
  s = red[0] + red[1] + red[2] + red[3];
  const float inv = 1.0f / s;
#pragma unroll
  for (int t = 0; t < 8; ++t) {
    const int idx = tid + (t << 8);
    if (idx < wlen) row[idx] = v[t] * inv;
  }
}

// ---------------------------------------------------------------------------
// 4) Grouped temporal conv (kernel 3, pad 1, groups=4) over v -> buf1.
//    buf1[b,t,o] = conv_b[o] + sum_{i,kk} v[b,t+kk-1, g*256+i]*w[o,i,kk]
// ---------------------------------------------------------------------------
#define CTT 16
__global__ __launch_bounds__(256) void k_conv(
    const float* __restrict__ v, const float* __restrict__ w,
    const float* __restrict__ cb, float* __restrict__ out)
{
  __shared__ float vb[(CTT + 2) * DDIM];
  const int t0 = blockIdx.x * CTT;
  const int b = blockIdx.y;
  const int tid = threadIdx.x;
  const float* vbase = v + (size_t)b * NSEQ * DDIM;
#pragma unroll
  for (int r = 0; r < CTT + 2; ++r) {
    const int t = t0 - 1 + r;
    float4 val = make_float4(0.f, 0.f, 0.f, 0.f);
    if (t >= 0 && t < NSEQ) val = *(const float4*)(vbase + (size_t)t * DDIM + (tid << 2));
    *(float4*)(vb + r * DDIM + (tid << 2)) = val;
  }
  __syncthreads();

  const int gg = tid >> 6;   // group (0..3), == wave id
  const int oo = tid & 63;
  int o[4];
#pragma unroll
  for (int oi = 0; oi < 4; ++oi) o[oi] = gg * 256 + oi * 64 + oo;
  float acc[4][CTT];
#pragma unroll
  for (int oi = 0; oi < 4; ++oi) {
    const float bias = cb[o[oi]];
#pragma unroll
    for (int t = 0; t < CTT; ++t) acc[oi][t] = bias;
  }
  const int chbase = gg << 8;
  for (int i = 0; i < 256; ++i) {
    float w0[4], w1[4], w2[4];
#pragma unroll
    for (int oi = 0; oi < 4; ++oi) {
      const float* wp = w + (size_t)o[oi] * 768 + i * 3;
      w0[oi] = wp[0]; w1[oi] = wp[1]; w2[oi] = wp[2];
    }
    float vv[CTT + 2];
#pragma unroll
    for (int r = 0; r < CTT + 2; ++r) vv[r] = vb[r * DDIM + chbase + i];
#pragma unroll
    for (int t = 0; t < CTT; ++t) {
#pragma unroll
      for (int oi = 0; oi < 4; ++oi) {
        acc[oi][t] = fmaf(vv[t], w0[oi],
                     fmaf(vv[t + 1], w1[oi],
                     fmaf(vv[t + 2], w2[oi], acc[oi][t])));
      }
    }
  }
  float* obase = out + (size_t)b * NSEQ * DDIM;
#pragma unroll
  for (int t = 0; t < CTT; ++t)
#pragma unroll
    for (int oi = 0; oi < 4; ++oi)
      obase[(size_t)(t0 + t) * DDIM + o[oi]] = acc[oi][t];
}

// ---------------------------------------------------------------------------
// 5) PV: buf1 += att @ v (causal: k-loop only up to diagonal tile)
// ---------------------------------------------------------------------------
__global__ __launch_bounds__(256) void k_pv(
    const float* __restrict__ att, const float* __restrict__ v,
    float* __restrict__ out)
{
  __shared__ float As[KC * LP];
  __shared__ float Bs[KC * LP];
  const int it = blockIdx.x, nt = blockIdx.y, b = blockIdx.z;
  const int row0 = it * TS;
  const int col0 = nt * TS;
  const int kmax = (it + 1) * TS;
  const float* A = att + (size_t)b * NSEQ * NSEQ;
  const float* B = v + (size_t)b * NSEQ * DDIM;
  float acc[4][4] = {};
  gemm_ab_body(A, B, NSEQ, DDIM, kmax, row0, col0, As, Bs, acc);
  const int cm = (threadIdx.x >> 4) << 2;
  const int cn = (threadIdx.x & 15) << 2;
  float* obase = out + (size_t)b * NSEQ * DDIM;
#pragma unroll
  for (int ii = 0; ii < 4; ++ii) {
    float* orow = obase + (size_t)(row0 + cm + ii) * DDIM + col0 + cn;
    float4 prev = *(const float4*)orow;
    prev.x += acc[ii][0]; prev.y += acc[ii][1];
    prev.z += acc[ii][2]; prev.w += acc[ii][3];
    *(float4*)orow = prev;
  }
}

// ---------------------------------------------------------------------------
// 6) Residual gate: g = sigmoid(buf1 @ resg_w^T + resg_b);
//    buf2 = x + g * buf1
// ---------------------------------------------------------------------------
__global__ __launch_bounds__(256) void k_resgate(
    const float* __restrict__ out1, const float* __restrict__ W,
    const float* __restrict__ bias, const float* __restrict__ x,
    float* __restrict__ out2)
{
  __shared__ float As[KC * LP];
  __shared__ float Bs[KC * LP];
  const int row0 = blockIdx.x * TS;
  const int col0 = blockIdx.y * TS;
  float acc[4][4] = {};
  gemm_bt_body(out1, W, DDIM, DDIM, DDIM, row0, col0, As, Bs, acc);
  const int cm = (threadIdx.x >> 4) << 2;
  const int cn = (threadIdx.x & 15) << 2;
#pragma unroll
  for (int ii = 0; ii < 4; ++ii) {
    const size_t base = (size_t)(row0 + cm + ii) * DDIM + col0 + cn;
    float4 xo = *(const float4*)(x + base);
    float4 o1 = *(const float4*)(out1 + base);
    float4 r;
    r.x = xo.x + sigmoidf_(acc[ii][0] + bias[col0 + cn + 0]) * o1.x;
    r.y = xo.y + sigmoidf_(acc[ii][1] + bias[col0 + cn + 1]) * o1.y;
    r.z = xo.z + sigmoidf_(acc[ii][2] + bias[col0 + cn + 2]) * o1.z;
    r.w = xo.w + sigmoidf_(acc[ii][3] + bias[col0 + cn + 3]) * o1.w;
    *(float4*)(out2 + base) = r;
  }
}

// ---------------------------------------------------------------------------
// 7) LayerNorm in place on buf2 (rows of 1024)
// ---------------------------------------------------------------------------
__global__ __launch_bounds__(256) void k_ln(
    float* __restrict__ buf, const float* __restrict__ gw,
    const float* __restrict__ gb)
{
  const int row = blockIdx.x;
  float* p = buf + (size_t)row * DDIM;
  const int tid = threadIdx.x;
  const int lane = tid & 63, wid = tid >> 6;
  const int c = tid << 2;
  float4 val = *(const float4*)(p + c);
  float s = val.x + val.y + val.z + val.w;
  float s2 = val.x * val.x + val.y * val.y + val.z * val.z + val.w * val.w;
#pragma unroll
  for (int off = 32; off; off >>= 1) {
    s += __shfl_xor(s, off);
    s2 += __shfl_xor(s2, off);
  }
  __shared__ float r1[4], r2[4];
  if (lane == 0) { r1[wid] = s; r2[wid] = s2; }
  __syncthreads();
  s = r1[0] + r1[1] + r1[2] + r1[3];
  s2 = r2[0] + r2[1] + r2[2] + r2[3];
  const float mean = s * (1.0f / DDIM);
  const float var = s2 * (1.0f / DDIM) - mean * mean;
  const float rstd = rsqrtf(var + 1e-5f);
  const float4 g4 = *(const float4*)(gw + c);
  const float4 b4 = *(const float4*)(gb + c);
  val.x = (val.x - mean) * rstd * g4.x + b4.x;
  val.y = (val.y - mean) * rstd * g4.y + b4.y;
  val.z = (val.z - mean) * rstd * g4.z + b4.z;
  val.w = (val.w - mean) * rstd * g4.w + b4.w;
  *(float4*)(p + c) = val;
}

// ---------------------------------------------------------------------------
// 8) fc1: h = gelu_exact(buf2 @ fc1_w^T + fc1_b)   ([8192,1024] -> [8192,512])
// ---------------------------------------------------------------------------
__global__ __launch_bounds__(256) void k_fc1(
    const float* __restrict__ A, const float* __restrict__ W,
    const float* __restrict__ bias, float* __restrict__ h)
{
  __shared__ float As[KC * LP];
  __shared__ float Bs[KC * LP];
  const int row0 = blockIdx.x * TS;
  const int col0 = blockIdx.y * TS;
  float acc[4][4] = {};
  gemm_bt_body(A, W, DDIM, DDIM, DDIM, row0, col0, As, Bs, acc);
  const int cm = (threadIdx.x >> 4) << 2;
  const int cn = (threadIdx.x & 15) << 2;
#pragma unroll
  for (int ii = 0; ii < 4; ++ii) {
    float4 r;
    float t0 = acc[ii][0] + bias[col0 + cn + 0];
    float t1 = acc[ii][1] + bias[col0 + cn + 1];
    float t2 = acc[ii][2] + bias[col0 + cn + 2];
    float t3 = acc[ii][3] + bias[col0 + cn + 3];
    r.x = 0.5f * t0 * (1.0f + erff(t0 * 0.70710678118654752f));
    r.y = 0.5f * t1 * (1.0f + erff(t1 * 0.70710678118654752f));
    r.z = 0.5f * t2 * (1.0f + erff(t2 * 0.70710678118654752f));
    r.w = 0.5f * t3 * (1.0f + erff(t3 * 0.70710678118654752f));
    *(float4*)(h + (size_t)(row0 + cm + ii) * 512 + col0 + cn) = r;
  }
}

// ---------------------------------------------------------------------------
// 9) fc2 + sigmoid: out[r] = sigmoid(h[r,:] . fc2_w + fc2_b)  (one wave/row)
// ---------------------------------------------------------------------------
__global__ __launch_bounds__(256) void k_fc2(
    const float* __restrict__ h, const float* __restrict__ w,
    const float* __restrict__ b2, float* __restrict__ out)
{
  const int r = blockIdx.x * 4 + (threadIdx.x >> 6);
  const int lane = threadIdx.x & 63;
  const float* hp = h + (size_t)r * 512;
  float s = 0.f;
#pragma unroll
  for (int t = 0; t < 8; ++t) {
    const int c = lane + t * 64;
    s = fmaf(hp[c], w[c], s);
  }
#pragma unroll
  for (int off = 32; off; off >>= 1) s += __shfl_xor(s, off);
  if (lane == 0) out[r] = sigmoidf_(s + b2[0]);
}

// ---------------------------------------------------------------------------
extern "C" void kernel_launch(void* const* d_in, const int* in_sizes, int n_in,
                              void* d_out, int out_size, void* d_ws, size_t ws_size,
                              hipStream_t stream) {
  const float* x    = (const float*)d_in[0];
  const float* Wq   = (const float*)d_in[1];
  const float* Wk   = (const float*)d_in[2];
  const float* Wv   = (const float*)d_in[3];
  const float* rb   = (const float*)d_in[4];
  const float* cw   = (const float*)d_in[5];
  const float* cb   = (const float*)d_in[6];
  const float* rw   = (const float*)d_in[7];
  const float* rbias= (const float*)d_in[8];
  const float* lng  = (const float*)d_in[9];
  const float* lnb  = (const float*)d_in[10];
  const float* f1w  = (const float*)d_in[11];
  const float* f1b  = (const float*)d_in[12];
  const float* f2w  = (const float*)d_in[13];
  const float* f2b  = (const float*)d_in[14];
  float* out = (float*)d_out;
  float* ws = (float*)d_ws;

  const size_t MD = (size_t)BSZ * NSEQ * DDIM;  // 8.39M floats
  float* q   = ws;
  float* k   = ws + MD;
  float* v   = ws + 2 * MD;
  float* att = ws + 3 * MD;                     // 4*2048*2048 floats
  // Aliases (lifetimes verified by launch order):
  float* buf1 = k;   // att_out + conv accumulator (k dead after k_scores)
  float* buf2 = q;   // gated/LN output           (q dead after k_scores)
  float* h    = v;   // fc1 output                (v dead after k_pv/k_conv)

  k_qkv    <<<dim3(128, 16, 3), 256, 0, stream>>>(x, Wq, Wk, Wv, q, k, v);
  k_scores <<<dim3(32, 32, BSZ), 256, 0, stream>>>(q, k, rb, att);
  k_softmax<<<dim3(NSEQ, BSZ),   256, 0, stream>>>(att);
  k_conv   <<<dim3(NSEQ / CTT, BSZ), 256, 0, stream>>>(v, cw, cb, buf1);
  k_pv     <<<dim3(32, 16, BSZ), 256, 0, stream>>>(att, v, buf1);
  k_resgate<<<dim3(128, 16),     256, 0, stream>>>(buf1, rw, rbias, x, buf2);
  k_ln     <<<dim3(BSZ * NSEQ),  256, 0, stream>>>(buf2, lng, lnb);
  k_fc1    <<<dim3(128, 8),      256, 0, stream>>>(buf2, f1w, f1b, h);
  k_fc2    <<<dim3(NSEQ),        256, 0, stream>>>(h, f2w, f2b, out);
}

// Round 2
// 619.631 us; speedup vs baseline: 3.9371x; 3.9371x over previous
//
#include <hip/hip_runtime.h>
#include <math.h>

#define NSEQ 2048
#define DDIM 1024
#define BSZ  4

// MFMA tile config: 128x128 block tile, 4 waves (2x2 of 64x64), BK=32
#define BM 128
#define BN 128
#define BK 32

typedef short bf16x8 __attribute__((ext_vector_type(8)));
typedef float f32x4 __attribute__((ext_vector_type(4)));

__device__ __forceinline__ unsigned short f2bf(float f) {
  union { float f; unsigned u; } x; x.f = f;
  unsigned r = x.u + 0x7FFFu + ((x.u >> 16) & 1u);
  return (unsigned short)(r >> 16);
}

__device__ __forceinline__ float sigmoidf_(float x) {
  return 1.0f / (1.0f + expf(-x));
}

// Stage a 128x32 fp32 tile (row-major, leading dim ld) into LDS as bf16.
// src must already point at (row0, 0); k0 selects the k-chunk.
__device__ __forceinline__ void stage_f32(const float* __restrict__ src, size_t ld,
                                          int k0, unsigned short* lds, int tid) {
#pragma unroll
  for (int p = 0; p < 4; ++p) {
    const int idx = p * 256 + tid;
    const int r = idx >> 3, kf = (idx & 7) << 2;
    const float4 v4 = *(const float4*)(src + (size_t)r * ld + k0 + kf);
    ushort4 o;
    o.x = f2bf(v4.x); o.y = f2bf(v4.y); o.z = f2bf(v4.z); o.w = f2bf(v4.w);
    *(ushort4*)(lds + r * BK + kf) = o;
  }
}

// Stage a 128x32 bf16 tile into LDS.
__device__ __forceinline__ void stage_bf16(const unsigned short* __restrict__ src, size_t ld,
                                           int k0, unsigned short* lds, int tid) {
#pragma unroll
  for (int p = 0; p < 4; ++p) {
    const int idx = p * 256 + tid;
    const int r = idx >> 3, kf = (idx & 7) << 2;
    *(ushort4*)(lds + r * BK + kf) = *(const ushort4*)(src + (size_t)r * ld + k0 + kf);
  }
}

// One BK=32 MFMA step: 4x4 frags of 16x16x32 per wave.
__device__ __forceinline__ void mfma_step(const unsigned short* Al, const unsigned short* Bl,
                                          int wr, int wc, int l16, int quad,
                                          f32x4 acc[4][4]) {
  bf16x8 a[4], b[4];
#pragma unroll
  for (int i = 0; i < 4; ++i) {
    a[i] = *(const bf16x8*)(Al + (wr * 64 + i * 16 + l16) * BK + quad * 8);
    b[i] = *(const bf16x8*)(Bl + (wc * 64 + i * 16 + l16) * BK + quad * 8);
  }
#pragma unroll
  for (int i = 0; i < 4; ++i)
#pragma unroll
    for (int j = 0; j < 4; ++j)
      acc[i][j] = __builtin_amdgcn_mfma_f32_16x16x32_bf16(a[i], b[j], acc[i][j], 0, 0, 0);
}

__device__ __forceinline__ void zero_acc(f32x4 acc[4][4]) {
#pragma unroll
  for (int i = 0; i < 4; ++i)
#pragma unroll
    for (int j = 0; j < 4; ++j) {
      f32x4 z = {0.f, 0.f, 0.f, 0.f};
      acc[i][j] = z;
    }
}

// ---------------------------------------------------------------------------
// 1) QKV: q,k (bf16 out) and v (fp32 out) = x @ W^T
// ---------------------------------------------------------------------------
__global__ __launch_bounds__(256) void k_qkv(
    const float* __restrict__ x,
    const float* __restrict__ Wq, const float* __restrict__ Wk,
    const float* __restrict__ Wv,
    unsigned short* __restrict__ qb, unsigned short* __restrict__ kb,
    float* __restrict__ v)
{
  __shared__ unsigned short Al[BM * BK], Bl[BN * BK];
  const int tid = threadIdx.x;
  const int z = blockIdx.z;
  const float* W = (z == 0) ? Wq : ((z == 1) ? Wk : Wv);
  const int row0 = blockIdx.x * BM, col0 = blockIdx.y * BN;
  const float* Abase = x + (size_t)row0 * DDIM;
  const float* Bbase = W + (size_t)col0 * DDIM;
  const int lane = tid & 63, wave = tid >> 6;
  const int quad = lane >> 4, l16 = lane & 15, wr = wave >> 1, wc = wave & 1;
  f32x4 acc[4][4];
  zero_acc(acc);
  for (int k0 = 0; k0 < DDIM; k0 += BK) {
    __syncthreads();
    stage_f32(Abase, DDIM, k0, Al, tid);
    stage_f32(Bbase, DDIM, k0, Bl, tid);
    __syncthreads();
    mfma_step(Al, Bl, wr, wc, l16, quad, acc);
  }
#pragma unroll
  for (int mi = 0; mi < 4; ++mi)
#pragma unroll
    for (int r = 0; r < 4; ++r) {
      const int grow = row0 + wr * 64 + mi * 16 + quad * 4 + r;
#pragma unroll
      for (int ni = 0; ni < 4; ++ni) {
        const int gcol = col0 + wc * 64 + ni * 16 + l16;
        const float val = acc[mi][ni][r];
        if (z == 0)      qb[(size_t)grow * DDIM + gcol] = f2bf(val);
        else if (z == 1) kb[(size_t)grow * DDIM + gcol] = f2bf(val);
        else             v [(size_t)grow * DDIM + gcol] = val;
      }
    }
}

// ---------------------------------------------------------------------------
// 2) v -> vT (bf16), per batch: vT[b][d][t]
// ---------------------------------------------------------------------------
__global__ __launch_bounds__(256) void k_vt(
    const float* __restrict__ v, unsigned short* __restrict__ vT)
{
  __shared__ float tile[64][65];
  const int t0 = blockIdx.x * 64, d0 = blockIdx.y * 64, b = blockIdx.z;
  const int tid = threadIdx.x;
  const float* vb = v + (size_t)b * NSEQ * DDIM;
#pragma unroll
  for (int p = 0; p < 4; ++p) {
    const int r = p * 16 + (tid >> 4);
    const int c = (tid & 15) << 2;
    const float4 v4 = *(const float4*)(vb + (size_t)(t0 + r) * DDIM + d0 + c);
    tile[r][c] = v4.x; tile[r][c + 1] = v4.y; tile[r][c + 2] = v4.z; tile[r][c + 3] = v4.w;
  }
  __syncthreads();
  unsigned short* ob = vT + (size_t)b * DDIM * NSEQ;
#pragma unroll
  for (int p = 0; p < 4; ++p) {
    const int d = p * 16 + (tid >> 4);
    const int t = (tid & 15) << 2;
    ushort4 o;
    o.x = f2bf(tile[t][d]); o.y = f2bf(tile[t + 1][d]);
    o.z = f2bf(tile[t + 2][d]); o.w = f2bf(tile[t + 3][d]);
    *(ushort4*)(ob + (size_t)(d0 + d) * NSEQ + t0 + t) = o;
  }
}

// ---------------------------------------------------------------------------
// 3) Scores: att = q k^T / 32 + rel_bias, causal-masked (fp32 out)
// ---------------------------------------------------------------------------
__global__ __launch_bounds__(256) void k_scores(
    const unsigned short* __restrict__ qb, const unsigned short* __restrict__ kb,
    const float* __restrict__ rb, float* __restrict__ att)
{
  const int it = blockIdx.x, jt = blockIdx.y, b = blockIdx.z;
  if (jt > it) return;
  __shared__ unsigned short Al[BM * BK], Bl[BN * BK];
  const int tid = threadIdx.x;
  const int row0 = it * BM, col0 = jt * BN;
  const unsigned short* Abase = qb + ((size_t)b * NSEQ + row0) * DDIM;
  const unsigned short* Bbase = kb + ((size_t)b * NSEQ + col0) * DDIM;
  const int lane = tid & 63, wave = tid >> 6;
  const int quad = lane >> 4, l16 = lane & 15, wr = wave >> 1, wc = wave & 1;
  f32x4 acc[4][4];
  zero_acc(acc);
  for (int k0 = 0; k0 < DDIM; k0 += BK) {
    __syncthreads();
    stage_bf16(Abase, DDIM, k0, Al, tid);
    stage_bf16(Bbase, DDIM, k0, Bl, tid);
    __syncthreads();
    mfma_step(Al, Bl, wr, wc, l16, quad, acc);
  }
  float* abase = att + (size_t)b * NSEQ * NSEQ;
#pragma unroll
  for (int mi = 0; mi < 4; ++mi)
#pragma unroll
    for (int r = 0; r < 4; ++r) {
      const int i = row0 + wr * 64 + mi * 16 + quad * 4 + r;
#pragma unroll
      for (int ni = 0; ni < 4; ++ni) {
        const int j = col0 + wc * 64 + ni * 16 + l16;
        const float val = acc[mi][ni][r] * 0.03125f + rb[(size_t)i * NSEQ + j];
        abase[(size_t)i * NSEQ + j] = (j <= i) ? val : -1e30f;
      }
    }
}

// ---------------------------------------------------------------------------
// 4) Row softmax (causal); zero-fills out to the 128-tile boundary.
// ---------------------------------------------------------------------------
__global__ __launch_bounds__(256) void k_softmax(float* __restrict__ att)
{
  const int i = blockIdx.x, b = blockIdx.y;
  float* row = att + ((size_t)b * NSEQ + i) * NSEQ;
  const int valid = i + 1;
  const int wlen = ((i >> 7) + 1) << 7;
  const int tid = threadIdx.x;
  const int lane = tid & 63, wid = tid >> 6;

  float v[8];
  float m = -1e30f;
#pragma unroll
  for (int t = 0; t < 8; ++t) {
    const int idx = tid + (t << 8);
    v[t] = (idx < valid) ? row[idx] : -1e30f;
    m = fmaxf(m, v[t]);
  }
#pragma unroll
  for (int off = 32; off; off >>= 1) m = fmaxf(m, __shfl_xor(m, off));
  __shared__ float red[4];
  if (lane == 0) red[wid] = m;
  __syncthreads();
  m = fmaxf(fmaxf(red[0], red[1]), fmaxf(red[2], red[3]));
  __syncthreads();

  float s = 0.f;
#pragma unroll
  for (int t = 0; t < 8; ++t) {
    const int idx = tid + (t << 8);
    float e = (idx < valid) ? expf(v[t] - m) : 0.f;
    v[t] = e;
    s += e;
  }
#pragma unroll
  for (int off = 32; off; off >>= 1) s += __shfl_xor(s, off);
  if (lane == 0) red[wid] = s;
  __syncthreads();
  s = red[0] + red[1] + red[2] + red[3];
  const float inv = 1.0f / s;
#pragma unroll
  for (int t = 0; t < 8; ++t) {
    const int idx = tid + (t << 8);
    if (idx < wlen) row[idx] = v[t] * inv;
  }
}

// ---------------------------------------------------------------------------
// 5) PV: buf1 = att @ v  (A fp32 staged, B = vT bf16), causal K limit
// ---------------------------------------------------------------------------
__global__ __launch_bounds__(256) void k_pv(
    const float* __restrict__ att, const unsigned short* __restrict__ vT,
    float* __restrict__ buf1)
{
  __shared__ unsigned short Al[BM * BK], Bl[BN * BK];
  const int it = blockIdx.x, nt = blockIdx.y, b = blockIdx.z;
  const int tid = threadIdx.x;
  const int row0 = it * BM, col0 = nt * BN;
  const float* Abase = att + ((size_t)b * NSEQ + row0) * NSEQ;
  const unsigned short* Bbase = vT + ((size_t)b * DDIM + col0) * NSEQ;
  const int K = (it + 1) * BM;
  const int lane = tid & 63, wave = tid >> 6;
  const int quad = lane >> 4, l16 = lane & 15, wr = wave >> 1, wc = wave & 1;
  f32x4 acc[4][4];
  zero_acc(acc);
  for (int k0 = 0; k0 < K; k0 += BK) {
    __syncthreads();
    stage_f32(Abase, NSEQ, k0, Al, tid);
    stage_bf16(Bbase, NSEQ, k0, Bl, tid);
    __syncthreads();
    mfma_step(Al, Bl, wr, wc, l16, quad, acc);
  }
  float* obase = buf1 + (size_t)b * NSEQ * DDIM;
#pragma unroll
  for (int mi = 0; mi < 4; ++mi)
#pragma unroll
    for (int r = 0; r < 4; ++r) {
      const int grow = row0 + wr * 64 + mi * 16 + quad * 4 + r;
#pragma unroll
      for (int ni = 0; ni < 4; ++ni) {
        const int gcol = col0 + wc * 64 + ni * 16 + l16;
        obase[(size_t)grow * DDIM + gcol] = acc[mi][ni][r];
      }
    }
}

// ---------------------------------------------------------------------------
// 6) Grouped conv as gathered-A GEMM over K'=768 (= in-ch x tap), += into buf1
// ---------------------------------------------------------------------------
__global__ __launch_bounds__(256) void k_conv(
    const float* __restrict__ v, const float* __restrict__ cw,
    const float* __restrict__ cb, float* __restrict__ buf1)
{
  __shared__ unsigned short Al[BM * BK], Bl[BN * BK];
  const int tid = threadIdx.x;
  const int row0 = blockIdx.x * BM;           // over b*NSEQ+t
  const int g = blockIdx.y >> 1, nc = blockIdx.y & 1;
  const int col0 = g * 256 + nc * 128;        // global output channel base
  const int b = row0 / NSEQ;
  const int t0 = row0 & (NSEQ - 1);
  const float* vb = v + (size_t)b * NSEQ * DDIM + g * 256;   // group in-ch base
  const float* Bbase = cw + (size_t)col0 * 768;
  const int lane = tid & 63, wave = tid >> 6;
  const int quad = lane >> 4, l16 = lane & 15, wr = wave >> 1, wc = wave & 1;
  f32x4 acc[4][4];
  zero_acc(acc);
  for (int c0 = 0; c0 < 768; c0 += BK) {
    __syncthreads();
    // gather A: element (m,kk): kp=c0+kk, i=kp/3, tap=kp%3, t=t0+m-1+tap
#pragma unroll
    for (int p = 0; p < 16; ++p) {
      const int idx = p * 256 + tid;
      const int m = idx >> 5, kk = idx & 31;
      const int kp = c0 + kk;
      const int i = kp / 3;
      const int tap = kp - i * 3;
      const int t = t0 + m - 1 + tap;
      const float val = (t >= 0 && t < NSEQ) ? vb[(size_t)t * DDIM + i] : 0.f;
      Al[m * BK + kk] = f2bf(val);
    }
    stage_f32(Bbase, 768, c0, Bl, tid);
    __syncthreads();
    mfma_step(Al, Bl, wr, wc, l16, quad, acc);
  }
#pragma unroll
  for (int mi = 0; mi < 4; ++mi)
#pragma unroll
    for (int r = 0; r < 4; ++r) {
      const int grow = row0 + wr * 64 + mi * 16 + quad * 4 + r;
#pragma unroll
      for (int ni = 0; ni < 4; ++ni) {
        const int gcol = col0 + wc * 64 + ni * 16 + l16;
        const size_t idx = (size_t)grow * DDIM + gcol;
        buf1[idx] += cb[gcol] + acc[mi][ni][r];
      }
    }
}

// ---------------------------------------------------------------------------
// 7) Residual gate: buf2 = x + sigmoid(buf1 @ rw^T + rb) * buf1
// ---------------------------------------------------------------------------
__global__ __launch_bounds__(256) void k_resgate(
    const float* __restrict__ buf1, const float* __restrict__ rw,
    const float* __restrict__ rbias, const float* __restrict__ x,
    float* __restrict__ buf2)
{
  __shared__ unsigned short Al[BM * BK], Bl[BN * BK];
  const int tid = threadIdx.x;
  const int row0 = blockIdx.x * BM, col0 = blockIdx.y * BN;
  const float* Abase = buf1 + (size_t)row0 * DDIM;
  const float* Bbase = rw + (size_t)col0 * DDIM;
  const int lane = tid & 63, wave = tid >> 6;
  const int quad = lane >> 4, l16 = lane & 15, wr = wave >> 1, wc = wave & 1;
  f32x4 acc[4][4];
  zero_acc(acc);
  for (int k0 = 0; k0 < DDIM; k0 += BK) {
    __syncthreads();
    stage_f32(Abase, DDIM, k0, Al, tid);
    stage_f32(Bbase, DDIM, k0, Bl, tid);
    __syncthreads();
    mfma_step(Al, Bl, wr, wc, l16, quad, acc);
  }
#pragma unroll
  for (int mi = 0; mi < 4; ++mi)
#pragma unroll
    for (int r = 0; r < 4; ++r) {
      const int grow = row0 + wr * 64 + mi * 16 + quad * 4 + r;
#pragma unroll
      for (int ni = 0; ni < 4; ++ni) {
        const int gcol = col0 + wc * 64 + ni * 16 + l16;
        const size_t idx = (size_t)grow * DDIM + gcol;
        const float gate = sigmoidf_(acc[mi][ni][r] + rbias[gcol]);
        buf2[idx] = x[idx] + gate * buf1[idx];
      }
    }
}

// ---------------------------------------------------------------------------
// 8) LayerNorm in place (rows of 1024)
// ---------------------------------------------------------------------------
__global__ __launch_bounds__(256) void k_ln(
    float* __restrict__ buf, const float* __restrict__ gw,
    const float* __restrict__ gb)
{
  const int row = blockIdx.x;
  float* p = buf + (size_t)row * DDIM;
  const int tid = threadIdx.x;
  const int lane = tid & 63, wid = tid >> 6;
  const int c = tid << 2;
  float4 val = *(const float4*)(p + c);
  float s = val.x + val.y + val.z + val.w;
  float s2 = val.x * val.x + val.y * val.y + val.z * val.z + val.w * val.w;
#pragma unroll
  for (int off = 32; off; off >>= 1) {
    s += __shfl_xor(s, off);
    s2 += __shfl_xor(s2, off);
  }
  __shared__ float r1[4], r2[4];
  if (lane == 0) { r1[wid] = s; r2[wid] = s2; }
  __syncthreads();
  s = r1[0] + r1[1] + r1[2] + r1[3];
  s2 = r2[0] + r2[1] + r2[2] + r2[3];
  const float mean = s * (1.0f / DDIM);
  const float var = s2 * (1.0f / DDIM) - mean * mean;
  const float rstd = rsqrtf(var + 1e-5f);
  const float4 g4 = *(const float4*)(gw + c);
  const float4 b4 = *(const float4*)(gb + c);
  val.x = (val.x - mean) * rstd * g4.x + b4.x;
  val.y = (val.y - mean) * rstd * g4.y + b4.y;
  val.z = (val.z - mean) * rstd * g4.z + b4.z;
  val.w = (val.w - mean) * rstd * g4.w + b4.w;
  *(float4*)(p + c) = val;
}

// ---------------------------------------------------------------------------
// 9) fc1 + exact GELU: h[8192,512]
// ---------------------------------------------------------------------------
__global__ __launch_bounds__(256) void k_fc1(
    const float* __restrict__ A, const float* __restrict__ W,
    const float* __restrict__ bias, float* __restrict__ h)
{
  __shared__ unsigned short Al[BM * BK], Bl[BN * BK];
  const int tid = threadIdx.x;
  const int row0 = blockIdx.x * BM, col0 = blockIdx.y * BN;
  const float* Abase = A + (size_t)row0 * DDIM;
  const float* Bbase = W + (size_t)col0 * DDIM;
  const int lane = tid & 63, wave = tid >> 6;
  const int quad = lane >> 4, l16 = lane & 15, wr = wave >> 1, wc = wave & 1;
  f32x4 acc[4][4];
  zero_acc(acc);
  for (int k0 = 0; k0 < DDIM; k0 += BK) {
    __syncthreads();
    stage_f32(Abase, DDIM, k0, Al, tid);
    stage_f32(Bbase, DDIM, k0, Bl, tid);
    __syncthreads();
    mfma_step(Al, Bl, wr, wc, l16, quad, acc);
  }
#pragma unroll
  for (int mi = 0; mi < 4; ++mi)
#pragma unroll
    for (int r = 0; r < 4; ++r) {
      const int grow = row0 + wr * 64 + mi * 16 + quad * 4 + r;
#pragma unroll
      for (int ni = 0; ni < 4; ++ni) {
        const int gcol = col0 + wc * 64 + ni * 16 + l16;
        const float t = acc[mi][ni][r] + bias[gcol];
        h[(size_t)grow * 512 + gcol] = 0.5f * t * (1.0f + erff(t * 0.70710678118654752f));
      }
    }
}

// ---------------------------------------------------------------------------
// 10) fc2 + sigmoid (one wave per row)
// ---------------------------------------------------------------------------
__global__ __launch_bounds__(256) void k_fc2(
    const float* __restrict__ h, const float* __restrict__ w,
    const float* __restrict__ b2, float* __restrict__ out)
{
  const int r = blockIdx.x * 4 + (threadIdx.x >> 6);
  const int lane = threadIdx.x & 63;
  const float* hp = h + (size_t)r * 512;
  float s = 0.f;
#pragma unroll
  for (int t = 0; t < 8; ++t) {
    const int c = lane + t * 64;
    s = fmaf(hp[c], w[c], s);
  }
#pragma unroll
  for (int off = 32; off; off >>= 1) s += __shfl_xor(s, off);
  if (lane == 0) out[r] = sigmoidf_(s + b2[0]);
}

// ---------------------------------------------------------------------------
extern "C" void kernel_launch(void* const* d_in, const int* in_sizes, int n_in,
                              void* d_out, int out_size, void* d_ws, size_t ws_size,
                              hipStream_t stream) {
  const float* x    = (const float*)d_in[0];
  const float* Wq   = (const float*)d_in[1];
  const float* Wk   = (const float*)d_in[2];
  const float* Wv   = (const float*)d_in[3];
  const float* rb   = (const float*)d_in[4];
  const float* cw   = (const float*)d_in[5];
  const float* cb   = (const float*)d_in[6];
  const float* rw   = (const float*)d_in[7];
  const float* rbias= (const float*)d_in[8];
  const float* lng  = (const float*)d_in[9];
  const float* lnb  = (const float*)d_in[10];
  const float* f1w  = (const float*)d_in[11];
  const float* f1b  = (const float*)d_in[12];
  const float* f2w  = (const float*)d_in[13];
  const float* f2b  = (const float*)d_in[14];
  float* out = (float*)d_out;
  char* w8 = (char*)d_ws;

  // Memory map (bytes):
  //   att  fp32 [4][2048][2048] : [0,          67108864)
  //   v    fp32 [4][2048][1024] : [67108864,  100663296)
  //   vT   bf16 [4][1024][2048] : [100663296, 117440512)
  //   qb   bf16 [8192][1024]    : [117440512, 134217728)
  //   kb   bf16 [8192][1024]    : [134217728, 150994944)
  // Aliases (lifetime-checked):
  //   buf1 fp32 [8192][1024] over qb+kb (dead after scores)
  //   buf2 fp32 [8192][1024] over att[0:33.5MB] (dead after PV/conv)
  //   h    fp32 [8192][512]  over vT (dead after PV)
  float* att = (float*)(w8);
  float* v   = (float*)(w8 + 67108864);
  unsigned short* vT = (unsigned short*)(w8 + 100663296);
  unsigned short* qb = (unsigned short*)(w8 + 117440512);
  unsigned short* kb = (unsigned short*)(w8 + 134217728);
  float* buf1 = (float*)(w8 + 117440512);
  float* buf2 = att;
  float* h    = (float*)(w8 + 100663296);

  k_qkv    <<<dim3(64, 8, 3),  256, 0, stream>>>(x, Wq, Wk, Wv, qb, kb, v);
  k_vt     <<<dim3(32, 16, 4), 256, 0, stream>>>(v, vT);
  k_scores <<<dim3(16, 16, 4), 256, 0, stream>>>(qb, kb, rb, att);
  k_softmax<<<dim3(NSEQ, BSZ), 256, 0, stream>>>(att);
  k_pv     <<<dim3(16, 8, 4),  256, 0, stream>>>(att, vT, buf1);
  k_conv   <<<dim3(64, 8),     256, 0, stream>>>(v, cw, cb, buf1);
  k_resgate<<<dim3(64, 8),     256, 0, stream>>>(buf1, rw, rbias, x, buf2);
  k_ln     <<<dim3(BSZ * NSEQ),256, 0, stream>>>(buf2, lng, lnb);
  k_fc1    <<<dim3(64, 4),     256, 0, stream>>>(buf2, f1w, f1b, h);
  k_fc2    <<<dim3(NSEQ),      256, 0, stream>>>(h, f2w, f2b, out);
}

// Round 3
// 444.822 us; speedup vs baseline: 5.4843x; 1.3930x over previous
//
#include <hip/hip_runtime.h>
#include <math.h>

#define NSEQ 2048
#define DDIM 1024
#define BSZ  4
#define BM 128
#define BN 128
#define BK 32

typedef short bf16x8 __attribute__((ext_vector_type(8)));
typedef float f32x4 __attribute__((ext_vector_type(4)));
typedef unsigned int u32;
typedef unsigned short u16;

__device__ __forceinline__ u16 f2bf(float f) {
  union { float f; u32 u; } x; x.f = f;
  u32 r = x.u + 0x7FFFu + ((x.u >> 16) & 1u);
  return (u16)(r >> 16);
}
__device__ __forceinline__ float bf2f(u16 h) {
  union { u32 u; float f; } x; x.u = ((u32)h) << 16; return x.f;
}
__device__ __forceinline__ float sigmoidf_(float x) {
  return 1.0f / (1.0f + expf(-x));
}

// Async 16B/lane global->LDS. LDS dest is wave-uniform base + lane*16.
__device__ __forceinline__ void async_copy16(const u16* g, u16* l) {
  __builtin_amdgcn_global_load_lds(
      (const __attribute__((address_space(1))) u32*)g,
      (__attribute__((address_space(3))) u32*)l, 16, 0, 0);
}

// Stage a 128x32 bf16 tile (row-major, leading dim ld elements) into LDS
// laid out [r][k] with row stride 32. 8 chunks of 16 rows; wave w takes
// chunks w and w+4. lane i: row = c*16 + (i>>2), col = (i&3)*8.
__device__ __forceinline__ void stage_tile(const u16* __restrict__ gsrc, size_t ld,
                                           int k0, u16* lds, int tid) {
  const int wave = tid >> 6, lane = tid & 63;
  const int rr = lane >> 2, cc = (lane & 3) << 3;
#pragma unroll
  for (int j = 0; j < 2; ++j) {
    const int c = j * 4 + wave;
    async_copy16(gsrc + (size_t)(c * 16 + rr) * ld + k0 + cc, lds + c * 512);
  }
}

// One BK=32 MFMA step: 4x4 frags of 16x16x32 per wave (2x2 wave grid).
__device__ __forceinline__ void mfma_step(const u16* Al, const u16* Bl,
                                          int wr, int wc, int l16, int quad,
                                          f32x4 acc[4][4]) {
  bf16x8 a[4], b[4];
#pragma unroll
  for (int i = 0; i < 4; ++i) {
    a[i] = *(const bf16x8*)(Al + (wr * 64 + i * 16 + l16) * BK + quad * 8);
    b[i] = *(const bf16x8*)(Bl + (wc * 64 + i * 16 + l16) * BK + quad * 8);
  }
#pragma unroll
  for (int i = 0; i < 4; ++i)
#pragma unroll
    for (int j = 0; j < 4; ++j)
      acc[i][j] = __builtin_amdgcn_mfma_f32_16x16x32_bf16(a[i], b[j], acc[i][j], 0, 0, 0);
}

__device__ __forceinline__ void zero_acc(f32x4 acc[4][4]) {
#pragma unroll
  for (int i = 0; i < 4; ++i)
#pragma unroll
    for (int j = 0; j < 4; ++j) {
      f32x4 z = {0.f, 0.f, 0.f, 0.f};
      acc[i][j] = z;
    }
}

__device__ __forceinline__ void gemm_loop(const u16* A, size_t lda,
                                          const u16* Bt, size_t ldb, int K,
                                          u16* Al, u16* Bl, int tid,
                                          int wr, int wc, int l16, int quad,
                                          f32x4 acc[4][4]) {
  for (int k0 = 0; k0 < K; k0 += BK) {
    __syncthreads();
    stage_tile(A, lda, k0, Al, tid);
    stage_tile(Bt, ldb, k0, Bl, tid);
    __syncthreads();
    mfma_step(Al, Bl, wr, wc, l16, quad, acc);
  }
}

// ---------------------------------------------------------------------------
// Prep: fp32 -> bf16 converts, conv-weight repack, v-pad zeroing
// ---------------------------------------------------------------------------
__global__ __launch_bounds__(256) void k_cvt(const float* __restrict__ s,
                                             u16* __restrict__ d, int n4) {
  const int i = blockIdx.x * 256 + threadIdx.x;
  if (i < n4) {
    const float4 v = ((const float4*)s)[i];
    ushort4 o;
    o.x = f2bf(v.x); o.y = f2bf(v.y); o.z = f2bf(v.z); o.w = f2bf(v.w);
    ((ushort4*)d)[i] = o;
  }
}

// cw [1024][256][3] fp32 -> cwp [o][tap*256+i] bf16
__global__ __launch_bounds__(256) void k_cvtconv(const float* __restrict__ s,
                                                 u16* __restrict__ d) {
  const int o = blockIdx.x, i = threadIdx.x;
#pragma unroll
  for (int tap = 0; tap < 3; ++tap)
    d[(size_t)o * 768 + tap * 256 + i] = f2bf(s[(size_t)o * 768 + i * 3 + tap]);
}

// zero the 8 pad rows of vpad ([4][2050][1024], rows 0 and 2049 per batch)
__global__ __launch_bounds__(256) void k_zeropad(u16* __restrict__ vpad) {
  const int bb = blockIdx.x >> 1, which = blockIdx.x & 1;
  u16* row = vpad + (size_t)bb * 2050 * 1024 + (which ? (size_t)2049 * 1024 : 0);
  ushort4 z = {0, 0, 0, 0};
  ((ushort4*)row)[threadIdx.x] = z;
}

// ---------------------------------------------------------------------------
// 1) QKV: qb,kb bf16 [8192][1024]; v bf16 into padded [4][2050][1024] layout
// ---------------------------------------------------------------------------
__global__ __launch_bounds__(256) void k_qkv(
    const u16* __restrict__ xb, const u16* __restrict__ Wqb,
    const u16* __restrict__ Wkb, const u16* __restrict__ Wvb,
    u16* __restrict__ qb, u16* __restrict__ kb, u16* __restrict__ vpad)
{
  __shared__ u16 Al[BM * BK], Bl[BN * BK];
  const int tid = threadIdx.x, z = blockIdx.z;
  const u16* W = (z == 0) ? Wqb : ((z == 1) ? Wkb : Wvb);
  const int row0 = blockIdx.x * BM, col0 = blockIdx.y * BN;
  const int lane = tid & 63, wave = tid >> 6;
  const int quad = lane >> 4, l16 = lane & 15, wr = wave >> 1, wc = wave & 1;
  f32x4 acc[4][4];
  zero_acc(acc);
  gemm_loop(xb + (size_t)row0 * DDIM, DDIM, W + (size_t)col0 * DDIM, DDIM, DDIM,
            Al, Bl, tid, wr, wc, l16, quad, acc);
#pragma unroll
  for (int mi = 0; mi < 4; ++mi)
#pragma unroll
    for (int r = 0; r < 4; ++r) {
      const int grow = row0 + wr * 64 + mi * 16 + quad * 4 + r;
#pragma unroll
      for (int ni = 0; ni < 4; ++ni) {
        const int gcol = col0 + wc * 64 + ni * 16 + l16;
        const u16 hv = f2bf(acc[mi][ni][r]);
        if (z == 2) {
          const int b = grow >> 11, t = grow & 2047;
          vpad[(size_t)b * 2050 * 1024 + 1024 + (size_t)t * 1024 + gcol] = hv;
        } else {
          (z == 0 ? qb : kb)[(size_t)grow * DDIM + gcol] = hv;
        }
      }
    }
}

// ---------------------------------------------------------------------------
// 2) v -> vT bf16 [b][d][t]
// ---------------------------------------------------------------------------
__global__ __launch_bounds__(256) void k_vt(const u16* __restrict__ vpad,
                                            u16* __restrict__ vT)
{
  __shared__ u16 tile[64][72];
  const int t0 = blockIdx.x * 64, d0 = blockIdx.y * 64, b = blockIdx.z;
  const int tid = threadIdx.x;
  const u16* vb = vpad + (size_t)b * 2050 * 1024 + 1024;
#pragma unroll
  for (int p = 0; p < 4; ++p) {
    const int r = p * 16 + (tid >> 4), c = (tid & 15) << 2;
    const ushort4 v4 = *(const ushort4*)(vb + (size_t)(t0 + r) * 1024 + d0 + c);
    tile[r][c] = v4.x; tile[r][c + 1] = v4.y; tile[r][c + 2] = v4.z; tile[r][c + 3] = v4.w;
  }
  __syncthreads();
  u16* ob = vT + (size_t)b * DDIM * NSEQ;
#pragma unroll
  for (int p = 0; p < 4; ++p) {
    const int d = p * 16 + (tid >> 4), t = (tid & 15) << 2;
    ushort4 o;
    o.x = tile[t][d]; o.y = tile[t + 1][d]; o.z = tile[t + 2][d]; o.w = tile[t + 3][d];
    *(ushort4*)(ob + (size_t)(d0 + d) * NSEQ + t0 + t) = o;
  }
}

// ---------------------------------------------------------------------------
// 3) Scores -> att bf16 (no masking; softmax only reads j<=i and overwrites)
// ---------------------------------------------------------------------------
__global__ __launch_bounds__(256) void k_scores(
    const u16* __restrict__ qb, const u16* __restrict__ kb,
    const float* __restrict__ rb, u16* __restrict__ att)
{
  const int it = blockIdx.x, jt = blockIdx.y, b = blockIdx.z;
  if (jt > it) return;
  __shared__ u16 Al[BM * BK], Bl[BN * BK];
  const int tid = threadIdx.x;
  const int row0 = it * BM, col0 = jt * BN;
  const int lane = tid & 63, wave = tid >> 6;
  const int quad = lane >> 4, l16 = lane & 15, wr = wave >> 1, wc = wave & 1;
  f32x4 acc[4][4];
  zero_acc(acc);
  gemm_loop(qb + ((size_t)b * NSEQ + row0) * DDIM, DDIM,
            kb + ((size_t)b * NSEQ + col0) * DDIM, DDIM, DDIM,
            Al, Bl, tid, wr, wc, l16, quad, acc);
  u16* abase = att + (size_t)b * NSEQ * NSEQ;
#pragma unroll
  for (int mi = 0; mi < 4; ++mi)
#pragma unroll
    for (int r = 0; r < 4; ++r) {
      const int i = row0 + wr * 64 + mi * 16 + quad * 4 + r;
#pragma unroll
      for (int ni = 0; ni < 4; ++ni) {
        const int j = col0 + wc * 64 + ni * 16 + l16;
        abase[(size_t)i * NSEQ + j] =
            f2bf(acc[mi][ni][r] * 0.03125f + rb[(size_t)i * NSEQ + j]);
      }
    }
}

// ---------------------------------------------------------------------------
// 4) Row softmax, bf16 in-place; zero-fills to the 128-tile boundary.
// ---------------------------------------------------------------------------
__global__ __launch_bounds__(256) void k_softmax(u16* __restrict__ att)
{
  const int i = blockIdx.x, b = blockIdx.y;
  u16* row = att + ((size_t)b * NSEQ + i) * NSEQ;
  const int valid = i + 1;
  const int wlen = ((i >> 7) + 1) << 7;
  const int tid = threadIdx.x;
  const int lane = tid & 63, wid = tid >> 6;

  float v[8];
  float m = -1e30f;
#pragma unroll
  for (int t = 0; t < 8; ++t) {
    const int idx = tid + (t << 8);
    v[t] = (idx < valid) ? bf2f(row[idx]) : -1e30f;
    m = fmaxf(m, v[t]);
  }
#pragma unroll
  for (int off = 32; off; off >>= 1) m = fmaxf(m, __shfl_xor(m, off));
  __shared__ float red[4];
  if (lane == 0) red[wid] = m;
  __syncthreads();
  m = fmaxf(fmaxf(red[0], red[1]), fmaxf(red[2], red[3]));
  __syncthreads();

  float s = 0.f;
#pragma unroll
  for (int t = 0; t < 8; ++t) {
    const int idx = tid + (t << 8);
    float e = (idx < valid) ? expf(v[t] - m) : 0.f;
    v[t] = e;
    s += e;
  }
#pragma unroll
  for (int off = 32; off; off >>= 1) s += __shfl_xor(s, off);
  if (lane == 0) red[wid] = s;
  __syncthreads();
  s = red[0] + red[1] + red[2] + red[3];
  const float inv = 1.0f / s;
#pragma unroll
  for (int t = 0; t < 8; ++t) {
    const int idx = tid + (t << 8);
    if (idx < wlen) row[idx] = f2bf(v[t] * inv);
  }
}

// ---------------------------------------------------------------------------
// 5) PV: buf1 = att @ v  (A = att bf16, B = vT bf16), causal K
// ---------------------------------------------------------------------------
__global__ __launch_bounds__(256) void k_pv(
    const u16* __restrict__ att, const u16* __restrict__ vT,
    float* __restrict__ buf1)
{
  __shared__ u16 Al[BM * BK], Bl[BN * BK];
  const int it = blockIdx.x, nt = blockIdx.y, b = blockIdx.z;
  const int tid = threadIdx.x;
  const int row0 = it * BM, col0 = nt * BN;
  const int K = (it + 1) * BM;
  const int lane = tid & 63, wave = tid >> 6;
  const int quad = lane >> 4, l16 = lane & 15, wr = wave >> 1, wc = wave & 1;
  f32x4 acc[4][4];
  zero_acc(acc);
  gemm_loop(att + ((size_t)b * NSEQ + row0) * NSEQ, NSEQ,
            vT + ((size_t)b * DDIM + col0) * NSEQ, NSEQ, K,
            Al, Bl, tid, wr, wc, l16, quad, acc);
  float* obase = buf1 + (size_t)b * NSEQ * DDIM;
#pragma unroll
  for (int mi = 0; mi < 4; ++mi)
#pragma unroll
    for (int r = 0; r < 4; ++r) {
      const int grow = row0 + wr * 64 + mi * 16 + quad * 4 + r;
#pragma unroll
      for (int ni = 0; ni < 4; ++ni) {
        const int gcol = col0 + wc * 64 + ni * 16 + l16;
        obase[(size_t)grow * DDIM + gcol] = acc[mi][ni][r];
      }
    }
}

// ---------------------------------------------------------------------------
// 6) Grouped conv as GEMM (K=768 tap-major), += into buf1, bf16 mirror buf1b
// ---------------------------------------------------------------------------
__global__ __launch_bounds__(256) void k_conv(
    const u16* __restrict__ vpad, const u16* __restrict__ cwp,
    const float* __restrict__ cb, float* __restrict__ buf1,
    u16* __restrict__ buf1b)
{
  __shared__ u16 Al[BM * BK], Bl[BN * BK];
  const int tid = threadIdx.x;
  const int row0 = blockIdx.x * BM;
  const int col0 = blockIdx.y * BN;
  const int g = col0 >> 8;
  const int b = row0 >> 11, t0 = row0 & 2047;
  const u16* vb = vpad + (size_t)b * 2050 * 1024 + 1024;
  const u16* Bbase = cwp + (size_t)col0 * 768;
  const int lane = tid & 63, wave = tid >> 6;
  const int quad = lane >> 4, l16 = lane & 15, wr = wave >> 1, wc = wave & 1;
  const int rr = lane >> 2, cc = (lane & 3) << 3;
  const int gch = g << 8;
  f32x4 acc[4][4];
  zero_acc(acc);
  for (int k0 = 0; k0 < 768; k0 += BK) {
    __syncthreads();
    const int tap = k0 >> 8;
    const int i0 = k0 & 255;
#pragma unroll
    for (int j = 0; j < 2; ++j) {
      const int c = j * 4 + wave;
      const int r = c * 16 + rr;
      // padded layout: t index in [-1, 2048] is always in-bounds
      async_copy16(vb + (size_t)(t0 + r - 1 + tap) * 1024 + gch + i0 + cc,
                   Al + c * 512);
    }
    stage_tile(Bbase, 768, k0, Bl, tid);
    __syncthreads();
    mfma_step(Al, Bl, wr, wc, l16, quad, acc);
  }
#pragma unroll
  for (int mi = 0; mi < 4; ++mi)
#pragma unroll
    for (int r = 0; r < 4; ++r) {
      const int grow = row0 + wr * 64 + mi * 16 + quad * 4 + r;
#pragma unroll
      for (int ni = 0; ni < 4; ++ni) {
        const int gcol = col0 + wc * 64 + ni * 16 + l16;
        const size_t idx = (size_t)grow * DDIM + gcol;
        const float val = buf1[idx] + cb[gcol] + acc[mi][ni][r];
        buf1[idx] = val;
        buf1b[idx] = f2bf(val);
      }
    }
}

// ---------------------------------------------------------------------------
// 7) Residual gate: buf2 = x + sigmoid(buf1 @ rw^T + rb) * buf1
// ---------------------------------------------------------------------------
__global__ __launch_bounds__(256) void k_resgate(
    const u16* __restrict__ buf1b, const u16* __restrict__ rwb,
    const float* __restrict__ rbias, const float* __restrict__ x,
    const float* __restrict__ buf1, float* __restrict__ buf2)
{
  __shared__ u16 Al[BM * BK], Bl[BN * BK];
  const int tid = threadIdx.x;
  const int row0 = blockIdx.x * BM, col0 = blockIdx.y * BN;
  const int lane = tid & 63, wave = tid >> 6;
  const int quad = lane >> 4, l16 = lane & 15, wr = wave >> 1, wc = wave & 1;
  f32x4 acc[4][4];
  zero_acc(acc);
  gemm_loop(buf1b + (size_t)row0 * DDIM, DDIM, rwb + (size_t)col0 * DDIM, DDIM,
            DDIM, Al, Bl, tid, wr, wc, l16, quad, acc);
#pragma unroll
  for (int mi = 0; mi < 4; ++mi)
#pragma unroll
    for (int r = 0; r < 4; ++r) {
      const int grow = row0 + wr * 64 + mi * 16 + quad * 4 + r;
#pragma unroll
      for (int ni = 0; ni < 4; ++ni) {
        const int gcol = col0 + wc * 64 + ni * 16 + l16;
        const size_t idx = (size_t)grow * DDIM + gcol;
        const float gate = sigmoidf_(acc[mi][ni][r] + rbias[gcol]);
        buf2[idx] = x[idx] + gate * buf1[idx];
      }
    }
}

// ---------------------------------------------------------------------------
// 8) LayerNorm: read buf2 fp32, write bf16 lnb16
// ---------------------------------------------------------------------------
__global__ __launch_bounds__(256) void k_ln(
    const float* __restrict__ buf, const float* __restrict__ gw,
    const float* __restrict__ gb, u16* __restrict__ outb)
{
  const int row = blockIdx.x;
  const float* p = buf + (size_t)row * DDIM;
  const int tid = threadIdx.x;
  const int lane = tid & 63, wid = tid >> 6;
  const int c = tid << 2;
  float4 val = *(const float4*)(p + c);
  float s = val.x + val.y + val.z + val.w;
  float s2 = val.x * val.x + val.y * val.y + val.z * val.z + val.w * val.w;
#pragma unroll
  for (int off = 32; off; off >>= 1) {
    s += __shfl_xor(s, off);
    s2 += __shfl_xor(s2, off);
  }
  __shared__ float r1[4], r2[4];
  if (lane == 0) { r1[wid] = s; r2[wid] = s2; }
  __syncthreads();
  s = r1[0] + r1[1] + r1[2] + r1[3];
  s2 = r2[0] + r2[1] + r2[2] + r2[3];
  const float mean = s * (1.0f / DDIM);
  const float var = s2 * (1.0f / DDIM) - mean * mean;
  const float rstd = rsqrtf(var + 1e-5f);
  const float4 g4 = *(const float4*)(gw + c);
  const float4 b4 = *(const float4*)(gb + c);
  ushort4 o;
  o.x = f2bf((val.x - mean) * rstd * g4.x + b4.x);
  o.y = f2bf((val.y - mean) * rstd * g4.y + b4.y);
  o.z = f2bf((val.z - mean) * rstd * g4.z + b4.z);
  o.w = f2bf((val.w - mean) * rstd * g4.w + b4.w);
  *(ushort4*)(outb + (size_t)row * DDIM + c) = o;
}

// ---------------------------------------------------------------------------
// 9) fc1 + exact GELU: h fp32 [8192][512]
// ---------------------------------------------------------------------------
__global__ __launch_bounds__(256) void k_fc1(
    const u16* __restrict__ A, const u16* __restrict__ W,
    const float* __restrict__ bias, float* __restrict__ h)
{
  __shared__ u16 Al[BM * BK], Bl[BN * BK];
  const int tid = threadIdx.x;
  const int row0 = blockIdx.x * BM, col0 = blockIdx.y * BN;
  const int lane = tid & 63, wave = tid >> 6;
  const int quad = lane >> 4, l16 = lane & 15, wr = wave >> 1, wc = wave & 1;
  f32x4 acc[4][4];
  zero_acc(acc);
  gemm_loop(A + (size_t)row0 * DDIM, DDIM, W + (size_t)col0 * DDIM, DDIM, DDIM,
            Al, Bl, tid, wr, wc, l16, quad, acc);
#pragma unroll
  for (int mi = 0; mi < 4; ++mi)
#pragma unroll
    for (int r = 0; r < 4; ++r) {
      const int grow = row0 + wr * 64 + mi * 16 + quad * 4 + r;
#pragma unroll
      for (int ni = 0; ni < 4; ++ni) {
        const int gcol = col0 + wc * 64 + ni * 16 + l16;
        const float t = acc[mi][ni][r] + bias[gcol];
        h[(size_t)grow * 512 + gcol] = 0.5f * t * (1.0f + erff(t * 0.70710678118654752f));
      }
    }
}

// ---------------------------------------------------------------------------
// 10) fc2 + sigmoid (one wave per row)
// ---------------------------------------------------------------------------
__global__ __launch_bounds__(256) void k_fc2(
    const float* __restrict__ h, const float* __restrict__ w,
    const float* __restrict__ b2, float* __restrict__ out)
{
  const int r = blockIdx.x * 4 + (threadIdx.x >> 6);
  const int lane = threadIdx.x & 63;
  const float* hp = h + (size_t)r * 512;
  float s = 0.f;
#pragma unroll
  for (int t = 0; t < 8; ++t) {
    const int c = lane + t * 64;
    s = fmaf(hp[c], w[c], s);
  }
#pragma unroll
  for (int off = 32; off; off >>= 1) s += __shfl_xor(s, off);
  if (lane == 0) out[r] = sigmoidf_(s + b2[0]);
}

// ---------------------------------------------------------------------------
extern "C" void kernel_launch(void* const* d_in, const int* in_sizes, int n_in,
                              void* d_out, int out_size, void* d_ws, size_t ws_size,
                              hipStream_t stream) {
  const float* x    = (const float*)d_in[0];
  const float* Wq   = (const float*)d_in[1];
  const float* Wk   = (const float*)d_in[2];
  const float* Wv   = (const float*)d_in[3];
  const float* rb   = (const float*)d_in[4];
  const float* cw   = (const float*)d_in[5];
  const float* cb   = (const float*)d_in[6];
  const float* rw   = (const float*)d_in[7];
  const float* rbias= (const float*)d_in[8];
  const float* lng  = (const float*)d_in[9];
  const float* lnb  = (const float*)d_in[10];
  const float* f1w  = (const float*)d_in[11];
  const float* f1b  = (const float*)d_in[12];
  const float* f2w  = (const float*)d_in[13];
  const float* f2b  = (const float*)d_in[14];
  float* out = (float*)d_out;
  char* w8 = (char*)d_ws;

  // Byte offsets (all 16B aligned). Peak use 128.5 MB.
  // Timeline aliases are lifetime-checked (see comments).
  u16* xb    = (u16*)(w8 + 0);           // 16.78M  (dead after qkv)
  u16* Wqb   = (u16*)(w8 + 16777216);    // 2M      (dead after qkv)
  u16* Wkb   = (u16*)(w8 + 18874368);    // 2M
  u16* Wvb   = (u16*)(w8 + 20971520);    // 2M
  u16* rwb   = (u16*)(w8 + 23068672);    // 2M      (until resgate)
  u16* f1wb  = (u16*)(w8 + 25165824);    // 1M      (until fc1)
  u16* cwp   = (u16*)(w8 + 26214400);    // 1.5M    (until conv)
  u16* qb    = (u16*)(w8 + 27787264);    // 16.78M  (dead after scores)
  u16* kb    = (u16*)(w8 + 44564480);    // 16.78M  (dead after scores)
  u16* vpad  = (u16*)(w8 + 61341696);    // 16.79M  (dead after conv)
  u16* vT    = (u16*)(w8 + 78131200);    // 16.78M  (dead after pv)
  u16* att   = (u16*)(w8 + 94908416);    // 33.55M  (dead after pv)
  float* buf1  = (float*)(w8 + 27787264);  // over qb+kb (written by pv)
  u16*   buf1b = (u16*)(w8 + 0);           // over xb (written by conv)
  float* buf2  = (float*)(w8 + 94908416);  // over att (written by resgate)
  u16*   ln16  = (u16*)(w8 + 78131200);    // over vT (written by ln)
  float* h     = (float*)(w8 + 61341696);  // over vpad (written by fc1)

  // Prep
  k_zeropad<<<dim3(8),    256, 0, stream>>>(vpad);
  k_cvt    <<<dim3(8192), 256, 0, stream>>>(x,   xb,   2097152);
  k_cvt    <<<dim3(1024), 256, 0, stream>>>(Wq,  Wqb,  262144);
  k_cvt    <<<dim3(1024), 256, 0, stream>>>(Wk,  Wkb,  262144);
  k_cvt    <<<dim3(1024), 256, 0, stream>>>(Wv,  Wvb,  262144);
  k_cvt    <<<dim3(1024), 256, 0, stream>>>(rw,  rwb,  262144);
  k_cvt    <<<dim3(512),  256, 0, stream>>>(f1w, f1wb, 131072);
  k_cvtconv<<<dim3(1024), 256, 0, stream>>>(cw, cwp);

  // Main pipeline
  k_qkv    <<<dim3(64, 8, 3),  256, 0, stream>>>(xb, Wqb, Wkb, Wvb, qb, kb, vpad);
  k_vt     <<<dim3(32, 16, 4), 256, 0, stream>>>(vpad, vT);
  k_scores <<<dim3(16, 16, 4), 256, 0, stream>>>(qb, kb, rb, att);
  k_softmax<<<dim3(NSEQ, BSZ), 256, 0, stream>>>(att);
  k_pv     <<<dim3(16, 8, 4),  256, 0, stream>>>(att, vT, buf1);
  k_conv   <<<dim3(64, 8),     256, 0, stream>>>(vpad, cwp, cb, buf1, buf1b);
  k_resgate<<<dim3(64, 8),     256, 0, stream>>>(buf1b, rwb, rbias, x, buf1, buf2);
  k_ln     <<<dim3(BSZ * NSEQ),256, 0, stream>>>(buf2, lng, lnb, ln16);
  k_fc1    <<<dim3(64, 4),     256, 0, stream>>>(ln16, f1wb, f1b, h);
  k_fc2    <<<dim3(NSEQ),      256, 0, stream>>>(h, f2w, f2b, out);
}

// Round 4
// 415.758 us; speedup vs baseline: 5.8677x; 1.0699x over previous
//
#include <hip/hip_runtime.h>
#include <math.h>

#define NSEQ 2048
#define DDIM 1024
#define BSZ  4
#define BM 128
#define BN 128
#define BK 32

typedef short bf16x8 __attribute__((ext_vector_type(8)));
typedef float f32x4 __attribute__((ext_vector_type(4)));
typedef unsigned int u32;
typedef unsigned short u16;

__device__ __forceinline__ u16 f2bf(float f) {
  union { float f; u32 u; } x; x.f = f;
  u32 r = x.u + 0x7FFFu + ((x.u >> 16) & 1u);
  return (u16)(r >> 16);
}
__device__ __forceinline__ float bf2f(u16 h) {
  union { u32 u; float f; } x; x.u = ((u32)h) << 16; return x.f;
}
__device__ __forceinline__ float sigmoidf_(float x) {
  return 1.0f / (1.0f + expf(-x));
}

// Async 16B/lane global->LDS. LDS dest is wave-uniform base + lane*16.
__device__ __forceinline__ void async_copy16(const u16* g, u16* l) {
  __builtin_amdgcn_global_load_lds(
      (const __attribute__((address_space(1))) u32*)g,
      (__attribute__((address_space(3))) u32*)l, 16, 0, 0);
}

// LDS tile layout: 8 chunks of 16 rows x 64B, XOR-swizzled 16B columns:
//   16B unit (row, q) lives at chunk + (row&15)*64 + (q ^ ((row>>1)&3))*16
// DMA writes lane->lane*16, so lane fetches global k-unit kg = cq ^ (rw>>1)&3.
// Read phases (16 lanes, fixed quad) then hit every bank exactly 2x (free).
__device__ __forceinline__ void stage_tile(const u16* __restrict__ gsrc, size_t ld,
                                           int k0, u16* lds, int tid) {
  const int wave = tid >> 6, lane = tid & 63;
  const int rr = lane >> 2;
  const int kg = (lane & 3) ^ ((lane >> 3) & 3);
  const int cc = kg << 3;
#pragma unroll
  for (int j = 0; j < 2; ++j) {
    const int c = j * 4 + wave;
    async_copy16(gsrc + (size_t)(c * 16 + rr) * ld + k0 + cc, lds + c * 512);
  }
}

// One BK=32 MFMA step: 4x4 frags of 16x16x32 per wave (2x2 wave grid).
__device__ __forceinline__ void mfma_step(const u16* Al, const u16* Bl,
                                          int wr, int wc, int l16, int quad,
                                          f32x4 acc[4][4]) {
  const int qs = (quad ^ ((l16 >> 1) & 3)) << 3;  // swizzled 16B column
  bf16x8 a[4], b[4];
#pragma unroll
  for (int i = 0; i < 4; ++i) {
    a[i] = *(const bf16x8*)(Al + (wr * 64 + i * 16 + l16) * BK + qs);
    b[i] = *(const bf16x8*)(Bl + (wc * 64 + i * 16 + l16) * BK + qs);
  }
#pragma unroll
  for (int i = 0; i < 4; ++i)
#pragma unroll
    for (int j = 0; j < 4; ++j)
      acc[i][j] = __builtin_amdgcn_mfma_f32_16x16x32_bf16(a[i], b[j], acc[i][j], 0, 0, 0);
}

__device__ __forceinline__ void zero_acc(f32x4 acc[4][4]) {
#pragma unroll
  for (int i = 0; i < 4; ++i)
#pragma unroll
    for (int j = 0; j < 4; ++j) {
      f32x4 z = {0.f, 0.f, 0.f, 0.f};
      acc[i][j] = z;
    }
}

__device__ __forceinline__ void gemm_loop(const u16* A, size_t lda,
                                          const u16* Bt, size_t ldb, int K,
                                          u16* Al, u16* Bl, int tid,
                                          int wr, int wc, int l16, int quad,
                                          f32x4 acc[4][4]) {
  for (int k0 = 0; k0 < K; k0 += BK) {
    __syncthreads();
    stage_tile(A, lda, k0, Al, tid);
    stage_tile(Bt, ldb, k0, Bl, tid);
    __syncthreads();
    mfma_step(Al, Bl, wr, wc, l16, quad, acc);
  }
}

// ---------------------------------------------------------------------------
// 0) Fused prep: all fp32->bf16 converts + conv-weight repack + v-pad zero.
// ---------------------------------------------------------------------------
__global__ __launch_bounds__(256) void k_prep(
    const float* __restrict__ x,  const float* __restrict__ Wq,
    const float* __restrict__ Wk, const float* __restrict__ Wv,
    const float* __restrict__ rw, const float* __restrict__ f1w,
    const float* __restrict__ cw,
    u16* __restrict__ xb,  u16* __restrict__ Wqb, u16* __restrict__ Wkb,
    u16* __restrict__ Wvb, u16* __restrict__ rwb, u16* __restrict__ f1wb,
    u16* __restrict__ cwp, u16* __restrict__ vpad)
{
  const int blk = blockIdx.x, tid = threadIdx.x;
  const float* s; u16* d; int base;
  if (blk < 8192)       { s = x;   d = xb;   base = blk; }
  else if (blk < 9216)  { s = Wq;  d = Wqb;  base = blk - 8192; }
  else if (blk < 10240) { s = Wk;  d = Wkb;  base = blk - 9216; }
  else if (blk < 11264) { s = Wv;  d = Wvb;  base = blk - 10240; }
  else if (blk < 12288) { s = rw;  d = rwb;  base = blk - 11264; }
  else if (blk < 12800) { s = f1w; d = f1wb; base = blk - 12288; }
  else if (blk < 13824) {
    const int o = blk - 12800, i = tid;
#pragma unroll
    for (int tap = 0; tap < 3; ++tap)
      cwp[(size_t)o * 768 + tap * 256 + i] = f2bf(cw[(size_t)o * 768 + i * 3 + tap]);
    return;
  } else {
    const int e = blk - 13824, bb = e >> 1, which = e & 1;
    u16* row = vpad + (size_t)bb * 2050 * 1024 + (which ? (size_t)2049 * 1024 : 0);
    ushort4 z = {0, 0, 0, 0};
    ((ushort4*)row)[tid] = z;
    return;
  }
  const int i = base * 256 + tid;
  const float4 v = ((const float4*)s)[i];
  ushort4 o;
  o.x = f2bf(v.x); o.y = f2bf(v.y); o.z = f2bf(v.z); o.w = f2bf(v.w);
  ((ushort4*)d)[i] = o;
}

// ---------------------------------------------------------------------------
// 1) QKV: qb,kb bf16 [8192][1024]; v bf16 into padded [4][2050][1024]
// ---------------------------------------------------------------------------
__global__ __launch_bounds__(256) void k_qkv(
    const u16* __restrict__ xb, const u16* __restrict__ Wqb,
    const u16* __restrict__ Wkb, const u16* __restrict__ Wvb,
    u16* __restrict__ qb, u16* __restrict__ kb, u16* __restrict__ vpad)
{
  __shared__ u16 Al[BM * BK], Bl[BN * BK];
  const int tid = threadIdx.x, z = blockIdx.z;
  const u16* W = (z == 0) ? Wqb : ((z == 1) ? Wkb : Wvb);
  const int row0 = blockIdx.x * BM, col0 = blockIdx.y * BN;
  const int lane = tid & 63, wave = tid >> 6;
  const int quad = lane >> 4, l16 = lane & 15, wr = wave >> 1, wc = wave & 1;
  f32x4 acc[4][4];
  zero_acc(acc);
  gemm_loop(xb + (size_t)row0 * DDIM, DDIM, W + (size_t)col0 * DDIM, DDIM, DDIM,
            Al, Bl, tid, wr, wc, l16, quad, acc);
#pragma unroll
  for (int mi = 0; mi < 4; ++mi)
#pragma unroll
    for (int r = 0; r < 4; ++r) {
      const int grow = row0 + wr * 64 + mi * 16 + quad * 4 + r;
#pragma unroll
      for (int ni = 0; ni < 4; ++ni) {
        const int gcol = col0 + wc * 64 + ni * 16 + l16;
        const u16 hv = f2bf(acc[mi][ni][r]);
        if (z == 2) {
          const int b = grow >> 11, t = grow & 2047;
          vpad[(size_t)b * 2050 * 1024 + 1024 + (size_t)t * 1024 + gcol] = hv;
        } else {
          (z == 0 ? qb : kb)[(size_t)grow * DDIM + gcol] = hv;
        }
      }
    }
}

// ---------------------------------------------------------------------------
// 2) v -> vT bf16 [b][d][t]
// ---------------------------------------------------------------------------
__global__ __launch_bounds__(256) void k_vt(const u16* __restrict__ vpad,
                                            u16* __restrict__ vT)
{
  __shared__ u16 tile[64][72];
  const int t0 = blockIdx.x * 64, d0 = blockIdx.y * 64, b = blockIdx.z;
  const int tid = threadIdx.x;
  const u16* vb = vpad + (size_t)b * 2050 * 1024 + 1024;
#pragma unroll
  for (int p = 0; p < 4; ++p) {
    const int r = p * 16 + (tid >> 4), c = (tid & 15) << 2;
    const ushort4 v4 = *(const ushort4*)(vb + (size_t)(t0 + r) * 1024 + d0 + c);
    tile[r][c] = v4.x; tile[r][c + 1] = v4.y; tile[r][c + 2] = v4.z; tile[r][c + 3] = v4.w;
  }
  __syncthreads();
  u16* ob = vT + (size_t)b * DDIM * NSEQ;
#pragma unroll
  for (int p = 0; p < 4; ++p) {
    const int d = p * 16 + (tid >> 4), t = (tid & 15) << 2;
    ushort4 o;
    o.x = tile[t][d]; o.y = tile[t + 1][d]; o.z = tile[t + 2][d]; o.w = tile[t + 3][d];
    *(ushort4*)(ob + (size_t)(d0 + d) * NSEQ + t0 + t) = o;
  }
}

// ---------------------------------------------------------------------------
// 3) Scores -> att FP32 (accuracy: no bf16 rounding before softmax)
// ---------------------------------------------------------------------------
__global__ __launch_bounds__(256) void k_scores(
    const u16* __restrict__ qb, const u16* __restrict__ kb,
    const float* __restrict__ rb, float* __restrict__ att)
{
  const int it = blockIdx.x, jt = blockIdx.y, b = blockIdx.z;
  if (jt > it) return;
  __shared__ u16 Al[BM * BK], Bl[BN * BK];
  const int tid = threadIdx.x;
  const int row0 = it * BM, col0 = jt * BN;
  const int lane = tid & 63, wave = tid >> 6;
  const int quad = lane >> 4, l16 = lane & 15, wr = wave >> 1, wc = wave & 1;
  f32x4 acc[4][4];
  zero_acc(acc);
  gemm_loop(qb + ((size_t)b * NSEQ + row0) * DDIM, DDIM,
            kb + ((size_t)b * NSEQ + col0) * DDIM, DDIM, DDIM,
            Al, Bl, tid, wr, wc, l16, quad, acc);
  float* abase = att + (size_t)b * NSEQ * NSEQ;
#pragma unroll
  for (int mi = 0; mi < 4; ++mi)
#pragma unroll
    for (int r = 0; r < 4; ++r) {
      const int i = row0 + wr * 64 + mi * 16 + quad * 4 + r;
#pragma unroll
      for (int ni = 0; ni < 4; ++ni) {
        const int j = col0 + wc * 64 + ni * 16 + l16;
        abase[(size_t)i * NSEQ + j] =
            acc[mi][ni][r] * 0.03125f + rb[(size_t)i * NSEQ + j];
      }
    }
}

// ---------------------------------------------------------------------------
// 4) Row softmax: fp32 in -> bf16 probs out; zero-fills to 128-boundary.
// ---------------------------------------------------------------------------
__global__ __launch_bounds__(256) void k_softmax(const float* __restrict__ att,
                                                 u16* __restrict__ attb)
{
  const int i = blockIdx.x, b = blockIdx.y;
  const float* row = att + ((size_t)b * NSEQ + i) * NSEQ;
  u16* orow = attb + ((size_t)b * NSEQ + i) * NSEQ;
  const int valid = i + 1;
  const int wlen = ((i >> 7) + 1) << 7;
  const int tid = threadIdx.x;
  const int lane = tid & 63, wid = tid >> 6;

  float v[8];
  float m = -1e30f;
#pragma unroll
  for (int t = 0; t < 8; ++t) {
    const int idx = tid + (t << 8);
    v[t] = (idx < valid) ? row[idx] : -1e30f;
    m = fmaxf(m, v[t]);
  }
#pragma unroll
  for (int off = 32; off; off >>= 1) m = fmaxf(m, __shfl_xor(m, off));
  __shared__ float red[4];
  if (lane == 0) red[wid] = m;
  __syncthreads();
  m = fmaxf(fmaxf(red[0], red[1]), fmaxf(red[2], red[3]));
  __syncthreads();

  float s = 0.f;
#pragma unroll
  for (int t = 0; t < 8; ++t) {
    const int idx = tid + (t << 8);
    float e = (idx < valid) ? expf(v[t] - m) : 0.f;
    v[t] = e;
    s += e;
  }
#pragma unroll
  for (int off = 32; off; off >>= 1) s += __shfl_xor(s, off);
  if (lane == 0) red[wid] = s;
  __syncthreads();
  s = red[0] + red[1] + red[2] + red[3];
  const float inv = 1.0f / s;
#pragma unroll
  for (int t = 0; t < 8; ++t) {
    const int idx = tid + (t << 8);
    if (idx < wlen) orow[idx] = f2bf(v[t] * inv);
  }
}

// ---------------------------------------------------------------------------
// 5) PV: buf1 = attb @ v  (bf16 x bf16), causal K
// ---------------------------------------------------------------------------
__global__ __launch_bounds__(256) void k_pv(
    const u16* __restrict__ attb, const u16* __restrict__ vT,
    float* __restrict__ buf1)
{
  __shared__ u16 Al[BM * BK], Bl[BN * BK];
  const int it = blockIdx.x, nt = blockIdx.y, b = blockIdx.z;
  const int tid = threadIdx.x;
  const int row0 = it * BM, col0 = nt * BN;
  const int K = (it + 1) * BM;
  const int lane = tid & 63, wave = tid >> 6;
  const int quad = lane >> 4, l16 = lane & 15, wr = wave >> 1, wc = wave & 1;
  f32x4 acc[4][4];
  zero_acc(acc);
  gemm_loop(attb + ((size_t)b * NSEQ + row0) * NSEQ, NSEQ,
            vT + ((size_t)b * DDIM + col0) * NSEQ, NSEQ, K,
            Al, Bl, tid, wr, wc, l16, quad, acc);
  float* obase = buf1 + (size_t)b * NSEQ * DDIM;
#pragma unroll
  for (int mi = 0; mi < 4; ++mi)
#pragma unroll
    for (int r = 0; r < 4; ++r) {
      const int grow = row0 + wr * 64 + mi * 16 + quad * 4 + r;
#pragma unroll
      for (int ni = 0; ni < 4; ++ni) {
        const int gcol = col0 + wc * 64 + ni * 16 + l16;
        obase[(size_t)grow * DDIM + gcol] = acc[mi][ni][r];
      }
    }
}

// ---------------------------------------------------------------------------
// 6) Grouped conv as GEMM (K=768 tap-major), += into buf1, bf16 mirror buf1b
// ---------------------------------------------------------------------------
__global__ __launch_bounds__(256) void k_conv(
    const u16* __restrict__ vpad, const u16* __restrict__ cwp,
    const float* __restrict__ cb, float* __restrict__ buf1,
    u16* __restrict__ buf1b)
{
  __shared__ u16 Al[BM * BK], Bl[BN * BK];
  const int tid = threadIdx.x;
  const int row0 = blockIdx.x * BM;
  const int col0 = blockIdx.y * BN;
  const int g = col0 >> 8;
  const int b = row0 >> 11, t0 = row0 & 2047;
  const u16* vb = vpad + (size_t)b * 2050 * 1024 + 1024;
  const u16* Bbase = cwp + (size_t)col0 * 768;
  const int lane = tid & 63, wave = tid >> 6;
  const int quad = lane >> 4, l16 = lane & 15, wr = wave >> 1, wc = wave & 1;
  const int rr = lane >> 2;
  const int kg = (lane & 3) ^ ((lane >> 3) & 3);   // swizzled global k-unit
  const int cc = kg << 3;
  const int gch = g << 8;
  f32x4 acc[4][4];
  zero_acc(acc);
  for (int k0 = 0; k0 < 768; k0 += BK) {
    __syncthreads();
    const int tap = k0 >> 8;
    const int i0 = k0 & 255;
#pragma unroll
    for (int j = 0; j < 2; ++j) {
      const int c = j * 4 + wave;
      const int r = c * 16 + rr;
      async_copy16(vb + (size_t)(t0 + r - 1 + tap) * 1024 + gch + i0 + cc,
                   Al + c * 512);
    }
    stage_tile(Bbase, 768, k0, Bl, tid);
    __syncthreads();
    mfma_step(Al, Bl, wr, wc, l16, quad, acc);
  }
#pragma unroll
  for (int mi = 0; mi < 4; ++mi)
#pragma unroll
    for (int r = 0; r < 4; ++r) {
      const int grow = row0 + wr * 64 + mi * 16 + quad * 4 + r;
#pragma unroll
      for (int ni = 0; ni < 4; ++ni) {
        const int gcol = col0 + wc * 64 + ni * 16 + l16;
        const size_t idx = (size_t)grow * DDIM + gcol;
        const float val = buf1[idx] + cb[gcol] + acc[mi][ni][r];
        buf1[idx] = val;
        buf1b[idx] = f2bf(val);
      }
    }
}

// ---------------------------------------------------------------------------
// 7) Residual gate: buf2 = x + sigmoid(buf1 @ rw^T + rb) * buf1
// ---------------------------------------------------------------------------
__global__ __launch_bounds__(256) void k_resgate(
    const u16* __restrict__ buf1b, const u16* __restrict__ rwb,
    const float* __restrict__ rbias, const float* __restrict__ x,
    const float* __restrict__ buf1, float* __restrict__ buf2)
{
  __shared__ u16 Al[BM * BK], Bl[BN * BK];
  const int tid = threadIdx.x;
  const int row0 = blockIdx.x * BM, col0 = blockIdx.y * BN;
  const int lane = tid & 63, wave = tid >> 6;
  const int quad = lane >> 4, l16 = lane & 15, wr = wave >> 1, wc = wave & 1;
  f32x4 acc[4][4];
  zero_acc(acc);
  gemm_loop(buf1b + (size_t)row0 * DDIM, DDIM, rwb + (size_t)col0 * DDIM, DDIM,
            DDIM, Al, Bl, tid, wr, wc, l16, quad, acc);
#pragma unroll
  for (int mi = 0; mi < 4; ++mi)
#pragma unroll
    for (int r = 0; r < 4; ++r) {
      const int grow = row0 + wr * 64 + mi * 16 + quad * 4 + r;
#pragma unroll
      for (int ni = 0; ni < 4; ++ni) {
        const int gcol = col0 + wc * 64 + ni * 16 + l16;
        const size_t idx = (size_t)grow * DDIM + gcol;
        const float gate = sigmoidf_(acc[mi][ni][r] + rbias[gcol]);
        buf2[idx] = x[idx] + gate * buf1[idx];
      }
    }
}

// ---------------------------------------------------------------------------
// 8) LayerNorm: read buf2 fp32, write bf16
// ---------------------------------------------------------------------------
__global__ __launch_bounds__(256) void k_ln(
    const float* __restrict__ buf, const float* __restrict__ gw,
    const float* __restrict__ gb, u16* __restrict__ outb)
{
  const int row = blockIdx.x;
  const float* p = buf + (size_t)row * DDIM;
  const int tid = threadIdx.x;
  const int lane = tid & 63, wid = tid >> 6;
  const int c = tid << 2;
  float4 val = *(const float4*)(p + c);
  float s = val.x + val.y + val.z + val.w;
  float s2 = val.x * val.x + val.y * val.y + val.z * val.z + val.w * val.w;
#pragma unroll
  for (int off = 32; off; off >>= 1) {
    s += __shfl_xor(s, off);
    s2 += __shfl_xor(s2, off);
  }
  __shared__ float r1[4], r2[4];
  if (lane == 0) { r1[wid] = s; r2[wid] = s2; }
  __syncthreads();
  s = r1[0] + r1[1] + r1[2] + r1[3];
  s2 = r2[0] + r2[1] + r2[2] + r2[3];
  const float mean = s * (1.0f / DDIM);
  const float var = s2 * (1.0f / DDIM) - mean * mean;
  const float rstd = rsqrtf(var + 1e-5f);
  const float4 g4 = *(const float4*)(gw + c);
  const float4 b4 = *(const float4*)(gb + c);
  ushort4 o;
  o.x = f2bf((val.x - mean) * rstd * g4.x + b4.x);
  o.y = f2bf((val.y - mean) * rstd * g4.y + b4.y);
  o.z = f2bf((val.z - mean) * rstd * g4.z + b4.z);
  o.w = f2bf((val.w - mean) * rstd * g4.w + b4.w);
  *(ushort4*)(outb + (size_t)row * DDIM + c) = o;
}

// ---------------------------------------------------------------------------
// 9) fc1 + exact GELU: h fp32 [8192][512]
// ---------------------------------------------------------------------------
__global__ __launch_bounds__(256) void k_fc1(
    const u16* __restrict__ A, const u16* __restrict__ W,
    const float* __restrict__ bias, float* __restrict__ h)
{
  __shared__ u16 Al[BM * BK], Bl[BN * BK];
  const int tid = threadIdx.x;
  const int row0 = blockIdx.x * BM, col0 = blockIdx.y * BN;
  const int lane = tid & 63, wave = tid >> 6;
  const int quad = lane >> 4, l16 = lane & 15, wr = wave >> 1, wc = wave & 1;
  f32x4 acc[4][4];
  zero_acc(acc);
  gemm_loop(A + (size_t)row0 * DDIM, DDIM, W + (size_t)col0 * DDIM, DDIM, DDIM,
            Al, Bl, tid, wr, wc, l16, quad, acc);
#pragma unroll
  for (int mi = 0; mi < 4; ++mi)
#pragma unroll
    for (int r = 0; r < 4; ++r) {
      const int grow = row0 + wr * 64 + mi * 16 + quad * 4 + r;
#pragma unroll
      for (int ni = 0; ni < 4; ++ni) {
        const int gcol = col0 + wc * 64 + ni * 16 + l16;
        const float t = acc[mi][ni][r] + bias[gcol];
        h[(size_t)grow * 512 + gcol] = 0.5f * t * (1.0f + erff(t * 0.70710678118654752f));
      }
    }
}

// ---------------------------------------------------------------------------
// 10) fc2 + sigmoid (one wave per row)
// ---------------------------------------------------------------------------
__global__ __launch_bounds__(256) void k_fc2(
    const float* __restrict__ h, const float* __restrict__ w,
    const float* __restrict__ b2, float* __restrict__ out)
{
  const int r = blockIdx.x * 4 + (threadIdx.x >> 6);
  const int lane = threadIdx.x & 63;
  const float* hp = h + (size_t)r * 512;
  float s = 0.f;
#pragma unroll
  for (int t = 0; t < 8; ++t) {
    const int c = lane + t * 64;
    s = fmaf(hp[c], w[c], s);
  }
#pragma unroll
  for (int off = 32; off; off >>= 1) s += __shfl_xor(s, off);
  if (lane == 0) out[r] = sigmoidf_(s + b2[0]);
}

// ---------------------------------------------------------------------------
extern "C" void kernel_launch(void* const* d_in, const int* in_sizes, int n_in,
                              void* d_out, int out_size, void* d_ws, size_t ws_size,
                              hipStream_t stream) {
  const float* x    = (const float*)d_in[0];
  const float* Wq   = (const float*)d_in[1];
  const float* Wk   = (const float*)d_in[2];
  const float* Wv   = (const float*)d_in[3];
  const float* rb   = (const float*)d_in[4];
  const float* cw   = (const float*)d_in[5];
  const float* cb   = (const float*)d_in[6];
  const float* rw   = (const float*)d_in[7];
  const float* rbias= (const float*)d_in[8];
  const float* lng  = (const float*)d_in[9];
  const float* lnb  = (const float*)d_in[10];
  const float* f1w  = (const float*)d_in[11];
  const float* f1b  = (const float*)d_in[12];
  const float* f2w  = (const float*)d_in[13];
  const float* f2b  = (const float*)d_in[14];
  float* out = (float*)d_out;
  char* w8 = (char*)d_ws;

  // Memory map (bytes), peak ~154.5 MB (< 167.8 MB known-good):
  u16* xb    = (u16*)(w8 + 0);           // 16.78M (dead after qkv)
  u16* Wqb   = (u16*)(w8 + 16777216);    // 2M
  u16* Wkb   = (u16*)(w8 + 18874368);    // 2M
  u16* Wvb   = (u16*)(w8 + 20971520);    // 2M
  u16* rwb   = (u16*)(w8 + 23068672);    // 2M (until resgate)
  u16* f1wb  = (u16*)(w8 + 25165824);    // 1M (until fc1)
  u16* cwp   = (u16*)(w8 + 26214400);    // 1.5M (until conv)
  u16* qb    = (u16*)(w8 + 27787264);    // 16.78M (dead after scores)
  u16* kb    = (u16*)(w8 + 44564480);    // 16.78M (dead after scores)
  u16* vpad  = (u16*)(w8 + 61341696);    // 16.79M (dead after conv)
  u16* vT    = (u16*)(w8 + 78135296);    // 16.78M (dead after pv)
  float* att = (float*)(w8 + 94912512);  // 67.1M fp32 (dead after softmax)
  // Aliases (lifetime-checked):
  u16*   attb  = (u16*)(w8 + 27787264);    // over qb+kb (softmax -> pv)
  float* buf1  = (float*)(w8 + 94912512);  // over att lower half (pv writes)
  u16*   buf1b = (u16*)(w8 + 0);           // over xb (conv writes)
  float* buf2  = (float*)(w8 + 128466944); // over att upper half (resgate)
  u16*   ln16  = (u16*)(w8 + 78135296);    // over vT (ln writes)
  float* h     = (float*)(w8 + 61341696);  // over vpad (fc1 writes)

  k_prep   <<<dim3(13832),     256, 0, stream>>>(x, Wq, Wk, Wv, rw, f1w, cw,
                                                 xb, Wqb, Wkb, Wvb, rwb, f1wb,
                                                 cwp, vpad);
  k_qkv    <<<dim3(64, 8, 3),  256, 0, stream>>>(xb, Wqb, Wkb, Wvb, qb, kb, vpad);
  k_vt     <<<dim3(32, 16, 4), 256, 0, stream>>>(vpad, vT);
  k_scores <<<dim3(16, 16, 4), 256, 0, stream>>>(qb, kb, rb, att);
  k_softmax<<<dim3(NSEQ, BSZ), 256, 0, stream>>>(att, attb);
  k_pv     <<<dim3(16, 8, 4),  256, 0, stream>>>(attb, vT, buf1);
  k_conv   <<<dim3(64, 8),     256, 0, stream>>>(vpad, cwp, cb, buf1, buf1b);
  k_resgate<<<dim3(64, 8),     256, 0, stream>>>(buf1b, rwb, rbias, x, buf1, buf2);
  k_ln     <<<dim3(BSZ * NSEQ),256, 0, stream>>>(buf2, lng, lnb, ln16);
  k_fc1    <<<dim3(64, 4),     256, 0, stream>>>(ln16, f1wb, f1b, h);
  k_fc2    <<<dim3(NSEQ),      256, 0, stream>>>(h, f2w, f2b, out);
}

// Round 5
// 383.820 us; speedup vs baseline: 6.3560x; 1.0832x over previous
//
#include <hip/hip_runtime.h>
#include <math.h>

#define NSEQ 2048
#define DDIM 1024
#define BSZ  4
#define BM 128
#define BN 128
#define BK 64   // 32 MFMAs per barrier-pair (2x the old BK=32)

typedef short bf16x8 __attribute__((ext_vector_type(8)));
typedef float f32x4 __attribute__((ext_vector_type(4)));
typedef unsigned int u32;
typedef unsigned short u16;

__device__ __forceinline__ u16 f2bf(float f) {
  union { float f; u32 u; } x; x.f = f;
  u32 r = x.u + 0x7FFFu + ((x.u >> 16) & 1u);
  return (u16)(r >> 16);
}
__device__ __forceinline__ float bf2f(u16 h) {
  union { u32 u; float f; } x; x.u = ((u32)h) << 16; return x.f;
}
__device__ __forceinline__ float sigmoidf_(float x) {
  return 1.0f / (1.0f + expf(-x));
}

// Async 16B/lane global->LDS. LDS dest is wave-uniform base + lane*16.
__device__ __forceinline__ void async_copy16(const u16* g, u16* l) {
  __builtin_amdgcn_global_load_lds(
      (const __attribute__((address_space(1))) u32*)g,
      (__attribute__((address_space(3))) u32*)l, 16, 0, 0);
}

// LDS tile: 128 rows x 64 bf16 (128B/row). 16 chunks of 8 rows (1KB each).
// XOR swizzle: global 16B-unit q of row r is stored at slot s = q ^ (r&7).
// DMA writes lane i -> chunk unit i (row = c*8 + i>>3, slot = i&7), so the
// lane fetches global unit q = (i&7) ^ ((i>>3)&7). Reads (16 lanes, fixed
// quad) then hit every bank exactly 2x -> conflict-free (m136: 2-way free).
__device__ __forceinline__ void stage_tile(const u16* __restrict__ gsrc, size_t ld,
                                           int k0, u16* lds, int tid) {
  const int wave = tid >> 6, lane = tid & 63;
  const int rr = lane >> 3;             // row within 8-row chunk
  const int q  = (lane & 7) ^ rr;       // swizzled global 16B-unit
#pragma unroll
  for (int j = 0; j < 4; ++j) {
    const int c = j * 4 + wave;         // chunk 0..15
    async_copy16(gsrc + (size_t)(c * 8 + rr) * ld + k0 + q * 8, lds + c * 512);
  }
}

// One BK=64 MFMA step: 2 k-substeps x 4x4 frags of 16x16x32 per wave.
__device__ __forceinline__ void mfma_step(const u16* Al, const u16* Bl,
                                          int wr, int wc, int l16, int quad,
                                          f32x4 acc[4][4]) {
  const int r7 = l16 & 7;
#pragma unroll
  for (int ks = 0; ks < 2; ++ks) {
    const int s = ((ks * 4 + quad) ^ r7) << 3;   // swizzled slot offset (u16)
    bf16x8 a[4], b[4];
#pragma unroll
    for (int i = 0; i < 4; ++i) {
      a[i] = *(const bf16x8*)(Al + (wr * 64 + i * 16 + l16) * BK + s);
      b[i] = *(const bf16x8*)(Bl + (wc * 64 + i * 16 + l16) * BK + s);
    }
#pragma unroll
    for (int i = 0; i < 4; ++i)
#pragma unroll
      for (int j = 0; j < 4; ++j)
        acc[i][j] = __builtin_amdgcn_mfma_f32_16x16x32_bf16(a[i], b[j], acc[i][j], 0, 0, 0);
  }
}

__device__ __forceinline__ void zero_acc(f32x4 acc[4][4]) {
#pragma unroll
  for (int i = 0; i < 4; ++i)
#pragma unroll
    for (int j = 0; j < 4; ++j) {
      f32x4 z = {0.f, 0.f, 0.f, 0.f};
      acc[i][j] = z;
    }
}

__device__ __forceinline__ void gemm_loop(const u16* A, size_t lda,
                                          const u16* Bt, size_t ldb, int K,
                                          u16* Al, u16* Bl, int tid,
                                          int wr, int wc, int l16, int quad,
                                          f32x4 acc[4][4]) {
  for (int k0 = 0; k0 < K; k0 += BK) {
    __syncthreads();
    stage_tile(A, lda, k0, Al, tid);
    stage_tile(Bt, ldb, k0, Bl, tid);
    __syncthreads();
    mfma_step(Al, Bl, wr, wc, l16, quad, acc);
  }
}

// ---------------------------------------------------------------------------
// 0) Fused prep: all fp32->bf16 converts + conv-weight repack + v-pad zero.
// ---------------------------------------------------------------------------
__global__ __launch_bounds__(256) void k_prep(
    const float* __restrict__ x,  const float* __restrict__ Wq,
    const float* __restrict__ Wk, const float* __restrict__ Wv,
    const float* __restrict__ rw, const float* __restrict__ f1w,
    const float* __restrict__ cw,
    u16* __restrict__ xb,  u16* __restrict__ Wqb, u16* __restrict__ Wkb,
    u16* __restrict__ Wvb, u16* __restrict__ rwb, u16* __restrict__ f1wb,
    u16* __restrict__ cwp, u16* __restrict__ vpad)
{
  const int blk = blockIdx.x, tid = threadIdx.x;
  const float* s; u16* d; int base;
  if (blk < 8192)       { s = x;   d = xb;   base = blk; }
  else if (blk < 9216)  { s = Wq;  d = Wqb;  base = blk - 8192; }
  else if (blk < 10240) { s = Wk;  d = Wkb;  base = blk - 9216; }
  else if (blk < 11264) { s = Wv;  d = Wvb;  base = blk - 10240; }
  else if (blk < 12288) { s = rw;  d = rwb;  base = blk - 11264; }
  else if (blk < 12800) { s = f1w; d = f1wb; base = blk - 12288; }
  else if (blk < 13824) {
    const int o = blk - 12800, i = tid;
#pragma unroll
    for (int tap = 0; tap < 3; ++tap)
      cwp[(size_t)o * 768 + tap * 256 + i] = f2bf(cw[(size_t)o * 768 + i * 3 + tap]);
    return;
  } else {
    const int e = blk - 13824, bb = e >> 1, which = e & 1;
    u16* row = vpad + (size_t)bb * 2050 * 1024 + (which ? (size_t)2049 * 1024 : 0);
    ushort4 z = {0, 0, 0, 0};
    ((ushort4*)row)[tid] = z;
    return;
  }
  const int i = base * 256 + tid;
  const float4 v = ((const float4*)s)[i];
  ushort4 o;
  o.x = f2bf(v.x); o.y = f2bf(v.y); o.z = f2bf(v.z); o.w = f2bf(v.w);
  ((ushort4*)d)[i] = o;
}

// ---------------------------------------------------------------------------
// 1) QKV: qb,kb bf16 [8192][1024]; v bf16 into padded [4][2050][1024]
// ---------------------------------------------------------------------------
__global__ __launch_bounds__(256) void k_qkv(
    const u16* __restrict__ xb, const u16* __restrict__ Wqb,
    const u16* __restrict__ Wkb, const u16* __restrict__ Wvb,
    u16* __restrict__ qb, u16* __restrict__ kb, u16* __restrict__ vpad)
{
  __shared__ u16 Al[BM * BK], Bl[BN * BK];
  const int tid = threadIdx.x, z = blockIdx.z;
  const u16* W = (z == 0) ? Wqb : ((z == 1) ? Wkb : Wvb);
  const int row0 = blockIdx.x * BM, col0 = blockIdx.y * BN;
  const int lane = tid & 63, wave = tid >> 6;
  const int quad = lane >> 4, l16 = lane & 15, wr = wave >> 1, wc = wave & 1;
  f32x4 acc[4][4];
  zero_acc(acc);
  gemm_loop(xb + (size_t)row0 * DDIM, DDIM, W + (size_t)col0 * DDIM, DDIM, DDIM,
            Al, Bl, tid, wr, wc, l16, quad, acc);
#pragma unroll
  for (int mi = 0; mi < 4; ++mi)
#pragma unroll
    for (int r = 0; r < 4; ++r) {
      const int grow = row0 + wr * 64 + mi * 16 + quad * 4 + r;
#pragma unroll
      for (int ni = 0; ni < 4; ++ni) {
        const int gcol = col0 + wc * 64 + ni * 16 + l16;
        const u16 hv = f2bf(acc[mi][ni][r]);
        if (z == 2) {
          const int b = grow >> 11, t = grow & 2047;
          vpad[(size_t)b * 2050 * 1024 + 1024 + (size_t)t * 1024 + gcol] = hv;
        } else {
          (z == 0 ? qb : kb)[(size_t)grow * DDIM + gcol] = hv;
        }
      }
    }
}

// ---------------------------------------------------------------------------
// 2) v -> vT bf16 [b][d][t]
// ---------------------------------------------------------------------------
__global__ __launch_bounds__(256) void k_vt(const u16* __restrict__ vpad,
                                            u16* __restrict__ vT)
{
  __shared__ u16 tile[64][72];
  const int t0 = blockIdx.x * 64, d0 = blockIdx.y * 64, b = blockIdx.z;
  const int tid = threadIdx.x;
  const u16* vb = vpad + (size_t)b * 2050 * 1024 + 1024;
#pragma unroll
  for (int p = 0; p < 4; ++p) {
    const int r = p * 16 + (tid >> 4), c = (tid & 15) << 2;
    const ushort4 v4 = *(const ushort4*)(vb + (size_t)(t0 + r) * 1024 + d0 + c);
    tile[r][c] = v4.x; tile[r][c + 1] = v4.y; tile[r][c + 2] = v4.z; tile[r][c + 3] = v4.w;
  }
  __syncthreads();
  u16* ob = vT + (size_t)b * DDIM * NSEQ;
#pragma unroll
  for (int p = 0; p < 4; ++p) {
    const int d = p * 16 + (tid >> 4), t = (tid & 15) << 2;
    ushort4 o;
    o.x = tile[t][d]; o.y = tile[t + 1][d]; o.z = tile[t + 2][d]; o.w = tile[t + 3][d];
    *(ushort4*)(ob + (size_t)(d0 + d) * NSEQ + t0 + t) = o;
  }
}

// ---------------------------------------------------------------------------
// 3) Scores -> att FP32 (no bf16 rounding before softmax; accuracy-critical)
// ---------------------------------------------------------------------------
__global__ __launch_bounds__(256) void k_scores(
    const u16* __restrict__ qb, const u16* __restrict__ kb,
    const float* __restrict__ rb, float* __restrict__ att)
{
  const int it = blockIdx.x, jt = blockIdx.y, b = blockIdx.z;
  if (jt > it) return;
  __shared__ u16 Al[BM * BK], Bl[BN * BK];
  const int tid = threadIdx.x;
  const int row0 = it * BM, col0 = jt * BN;
  const int lane = tid & 63, wave = tid >> 6;
  const int quad = lane >> 4, l16 = lane & 15, wr = wave >> 1, wc = wave & 1;
  f32x4 acc[4][4];
  zero_acc(acc);
  gemm_loop(qb + ((size_t)b * NSEQ + row0) * DDIM, DDIM,
            kb + ((size_t)b * NSEQ + col0) * DDIM, DDIM, DDIM,
            Al, Bl, tid, wr, wc, l16, quad, acc);
  float* abase = att + (size_t)b * NSEQ * NSEQ;
#pragma unroll
  for (int mi = 0; mi < 4; ++mi)
#pragma unroll
    for (int r = 0; r < 4; ++r) {
      const int i = row0 + wr * 64 + mi * 16 + quad * 4 + r;
#pragma unroll
      for (int ni = 0; ni < 4; ++ni) {
        const int j = col0 + wc * 64 + ni * 16 + l16;
        abase[(size_t)i * NSEQ + j] =
            acc[mi][ni][r] * 0.03125f + rb[(size_t)i * NSEQ + j];
      }
    }
}

// ---------------------------------------------------------------------------
// 4) Row softmax: fp32 in -> bf16 probs out; zero-fills to 128-boundary.
// ---------------------------------------------------------------------------
__global__ __launch_bounds__(256) void k_softmax(const float* __restrict__ att,
                                                 u16* __restrict__ attb)
{
  const int i = blockIdx.x, b = blockIdx.y;
  const float* row = att + ((size_t)b * NSEQ + i) * NSEQ;
  u16* orow = attb + ((size_t)b * NSEQ + i) * NSEQ;
  const int valid = i + 1;
  const int wlen = ((i >> 7) + 1) << 7;
  const int tid = threadIdx.x;
  const int lane = tid & 63, wid = tid >> 6;

  float v[8];
  float m = -1e30f;
#pragma unroll
  for (int t = 0; t < 8; ++t) {
    const int idx = tid + (t << 8);
    v[t] = (idx < valid) ? row[idx] : -1e30f;
    m = fmaxf(m, v[t]);
  }
#pragma unroll
  for (int off = 32; off; off >>= 1) m = fmaxf(m, __shfl_xor(m, off));
  __shared__ float red[4];
  if (lane == 0) red[wid] = m;
  __syncthreads();
  m = fmaxf(fmaxf(red[0], red[1]), fmaxf(red[2], red[3]));
  __syncthreads();

  float s = 0.f;
#pragma unroll
  for (int t = 0; t < 8; ++t) {
    const int idx = tid + (t << 8);
    float e = (idx < valid) ? expf(v[t] - m) : 0.f;
    v[t] = e;
    s += e;
  }
#pragma unroll
  for (int off = 32; off; off >>= 1) s += __shfl_xor(s, off);
  if (lane == 0) red[wid] = s;
  __syncthreads();
  s = red[0] + red[1] + red[2] + red[3];
  const float inv = 1.0f / s;
#pragma unroll
  for (int t = 0; t < 8; ++t) {
    const int idx = tid + (t << 8);
    if (idx < wlen) orow[idx] = f2bf(v[t] * inv);
  }
}

// ---------------------------------------------------------------------------
// 5) PV: pvb(bf16) = attb @ v, causal K
// ---------------------------------------------------------------------------
__global__ __launch_bounds__(256) void k_pv(
    const u16* __restrict__ attb, const u16* __restrict__ vT,
    u16* __restrict__ pvb)
{
  __shared__ u16 Al[BM * BK], Bl[BN * BK];
  const int it = blockIdx.x, nt = blockIdx.y, b = blockIdx.z;
  const int tid = threadIdx.x;
  const int row0 = it * BM, col0 = nt * BN;
  const int K = (it + 1) * BM;
  const int lane = tid & 63, wave = tid >> 6;
  const int quad = lane >> 4, l16 = lane & 15, wr = wave >> 1, wc = wave & 1;
  f32x4 acc[4][4];
  zero_acc(acc);
  gemm_loop(attb + ((size_t)b * NSEQ + row0) * NSEQ, NSEQ,
            vT + ((size_t)b * DDIM + col0) * NSEQ, NSEQ, K,
            Al, Bl, tid, wr, wc, l16, quad, acc);
  u16* obase = pvb + (size_t)b * NSEQ * DDIM;
#pragma unroll
  for (int mi = 0; mi < 4; ++mi)
#pragma unroll
    for (int r = 0; r < 4; ++r) {
      const int grow = row0 + wr * 64 + mi * 16 + quad * 4 + r;
#pragma unroll
      for (int ni = 0; ni < 4; ++ni) {
        const int gcol = col0 + wc * 64 + ni * 16 + l16;
        obase[(size_t)grow * DDIM + gcol] = f2bf(acc[mi][ni][r]);
      }
    }
}

// ---------------------------------------------------------------------------
// 6) Grouped conv as GEMM (K=768 tap-major): buf1b = pvb + conv + bias (bf16)
// ---------------------------------------------------------------------------
__global__ __launch_bounds__(256) void k_conv(
    const u16* __restrict__ vpad, const u16* __restrict__ cwp,
    const float* __restrict__ cb, const u16* __restrict__ pvb,
    u16* __restrict__ buf1b)
{
  __shared__ u16 Al[BM * BK], Bl[BN * BK];
  const int tid = threadIdx.x;
  const int row0 = blockIdx.x * BM;
  const int col0 = blockIdx.y * BN;
  const int g = col0 >> 8;
  const int b = row0 >> 11, t0 = row0 & 2047;
  const u16* vb = vpad + (size_t)b * 2050 * 1024 + 1024;
  const u16* Bbase = cwp + (size_t)col0 * 768;
  const int lane = tid & 63, wave = tid >> 6;
  const int quad = lane >> 4, l16 = lane & 15, wr = wave >> 1, wc = wave & 1;
  const int rr = lane >> 3;
  const int q  = (lane & 7) ^ rr;
  const int gch = g << 8;
  f32x4 acc[4][4];
  zero_acc(acc);
  for (int k0 = 0; k0 < 768; k0 += BK) {
    __syncthreads();
    const int tap = k0 >> 8;          // 64-chunks never cross tap boundaries
    const int i0 = k0 & 255;
#pragma unroll
    for (int j = 0; j < 4; ++j) {
      const int c = j * 4 + wave;
      const int r = c * 8 + rr;
      async_copy16(vb + (size_t)(t0 + r - 1 + tap) * 1024 + gch + i0 + q * 8,
                   Al + c * 512);
    }
    stage_tile(Bbase, 768, k0, Bl, tid);
    __syncthreads();
    mfma_step(Al, Bl, wr, wc, l16, quad, acc);
  }
#pragma unroll
  for (int mi = 0; mi < 4; ++mi)
#pragma unroll
    for (int r = 0; r < 4; ++r) {
      const int grow = row0 + wr * 64 + mi * 16 + quad * 4 + r;
#pragma unroll
      for (int ni = 0; ni < 4; ++ni) {
        const int gcol = col0 + wc * 64 + ni * 16 + l16;
        const size_t idx = (size_t)grow * DDIM + gcol;
        buf1b[idx] = f2bf(bf2f(pvb[idx]) + cb[gcol] + acc[mi][ni][r]);
      }
    }
}

// ---------------------------------------------------------------------------
// 7) Residual gate: buf2(bf16) = x + sigmoid(buf1b @ rw^T + rb) * buf1b
// ---------------------------------------------------------------------------
__global__ __launch_bounds__(256) void k_resgate(
    const u16* __restrict__ buf1b, const u16* __restrict__ rwb,
    const float* __restrict__ rbias, const float* __restrict__ x,
    u16* __restrict__ buf2)
{
  __shared__ u16 Al[BM * BK], Bl[BN * BK];
  const int tid = threadIdx.x;
  const int row0 = blockIdx.x * BM, col0 = blockIdx.y * BN;
  const int lane = tid & 63, wave = tid >> 6;
  const int quad = lane >> 4, l16 = lane & 15, wr = wave >> 1, wc = wave & 1;
  f32x4 acc[4][4];
  zero_acc(acc);
  gemm_loop(buf1b + (size_t)row0 * DDIM, DDIM, rwb + (size_t)col0 * DDIM, DDIM,
            DDIM, Al, Bl, tid, wr, wc, l16, quad, acc);
#pragma unroll
  for (int mi = 0; mi < 4; ++mi)
#pragma unroll
    for (int r = 0; r < 4; ++r) {
      const int grow = row0 + wr * 64 + mi * 16 + quad * 4 + r;
#pragma unroll
      for (int ni = 0; ni < 4; ++ni) {
        const int gcol = col0 + wc * 64 + ni * 16 + l16;
        const size_t idx = (size_t)grow * DDIM + gcol;
        const float gate = sigmoidf_(acc[mi][ni][r] + rbias[gcol]);
        buf2[idx] = f2bf(x[idx] + gate * bf2f(buf1b[idx]));
      }
    }
}

// ---------------------------------------------------------------------------
// 8) LayerNorm: bf16 in -> bf16 out (stats in fp32)
// ---------------------------------------------------------------------------
__global__ __launch_bounds__(256) void k_ln(
    const u16* __restrict__ buf, const float* __restrict__ gw,
    const float* __restrict__ gb, u16* __restrict__ outb)
{
  const int row = blockIdx.x;
  const u16* p = buf + (size_t)row * DDIM;
  const int tid = threadIdx.x;
  const int lane = tid & 63, wid = tid >> 6;
  const int c = tid << 2;
  const ushort4 raw = *(const ushort4*)(p + c);
  float4 val;
  val.x = bf2f(raw.x); val.y = bf2f(raw.y); val.z = bf2f(raw.z); val.w = bf2f(raw.w);
  float s = val.x + val.y + val.z + val.w;
  float s2 = val.x * val.x + val.y * val.y + val.z * val.z + val.w * val.w;
#pragma unroll
  for (int off = 32; off; off >>= 1) {
    s += __shfl_xor(s, off);
    s2 += __shfl_xor(s2, off);
  }
  __shared__ float r1[4], r2[4];
  if (lane == 0) { r1[wid] = s; r2[wid] = s2; }
  __syncthreads();
  s = r1[0] + r1[1] + r1[2] + r1[3];
  s2 = r2[0] + r2[1] + r2[2] + r2[3];
  const float mean = s * (1.0f / DDIM);
  const float var = s2 * (1.0f / DDIM) - mean * mean;
  const float rstd = rsqrtf(var + 1e-5f);
  const float4 g4 = *(const float4*)(gw + c);
  const float4 b4 = *(const float4*)(gb + c);
  ushort4 o;
  o.x = f2bf((val.x - mean) * rstd * g4.x + b4.x);
  o.y = f2bf((val.y - mean) * rstd * g4.y + b4.y);
  o.z = f2bf((val.z - mean) * rstd * g4.z + b4.z);
  o.w = f2bf((val.w - mean) * rstd * g4.w + b4.w);
  *(ushort4*)(outb + (size_t)row * DDIM + c) = o;
}

// ---------------------------------------------------------------------------
// 9) fc1 + exact GELU: h bf16 [8192][512]
// ---------------------------------------------------------------------------
__global__ __launch_bounds__(256) void k_fc1(
    const u16* __restrict__ A, const u16* __restrict__ W,
    const float* __restrict__ bias, u16* __restrict__ h)
{
  __shared__ u16 Al[BM * BK], Bl[BN * BK];
  const int tid = threadIdx.x;
  const int row0 = blockIdx.x * BM, col0 = blockIdx.y * BN;
  const int lane = tid & 63, wave = tid >> 6;
  const int quad = lane >> 4, l16 = lane & 15, wr = wave >> 1, wc = wave & 1;
  f32x4 acc[4][4];
  zero_acc(acc);
  gemm_loop(A + (size_t)row0 * DDIM, DDIM, W + (size_t)col0 * DDIM, DDIM, DDIM,
            Al, Bl, tid, wr, wc, l16, quad, acc);
#pragma unroll
  for (int mi = 0; mi < 4; ++mi)
#pragma unroll
    for (int r = 0; r < 4; ++r) {
      const int grow = row0 + wr * 64 + mi * 16 + quad * 4 + r;
#pragma unroll
      for (int ni = 0; ni < 4; ++ni) {
        const int gcol = col0 + wc * 64 + ni * 16 + l16;
        const float t = acc[mi][ni][r] + bias[gcol];
        h[(size_t)grow * 512 + gcol] =
            f2bf(0.5f * t * (1.0f + erff(t * 0.70710678118654752f)));
      }
    }
}

// ---------------------------------------------------------------------------
// 10) fc2 + sigmoid (one wave per row), bf16 h
// ---------------------------------------------------------------------------
__global__ __launch_bounds__(256) void k_fc2(
    const u16* __restrict__ h, const float* __restrict__ w,
    const float* __restrict__ b2, float* __restrict__ out)
{
  const int r = blockIdx.x * 4 + (threadIdx.x >> 6);
  const int lane = threadIdx.x & 63;
  const u16* hp = h + (size_t)r * 512;
  float s = 0.f;
#pragma unroll
  for (int t = 0; t < 8; ++t) {
    const int c = lane + t * 64;
    s = fmaf(bf2f(hp[c]), w[c], s);
  }
#pragma unroll
  for (int off = 32; off; off >>= 1) s += __shfl_xor(s, off);
  if (lane == 0) out[r] = sigmoidf_(s + b2[0]);
}

// ---------------------------------------------------------------------------
extern "C" void kernel_launch(void* const* d_in, const int* in_sizes, int n_in,
                              void* d_out, int out_size, void* d_ws, size_t ws_size,
                              hipStream_t stream) {
  const float* x    = (const float*)d_in[0];
  const float* Wq   = (const float*)d_in[1];
  const float* Wk   = (const float*)d_in[2];
  const float* Wv   = (const float*)d_in[3];
  const float* rb   = (const float*)d_in[4];
  const float* cw   = (const float*)d_in[5];
  const float* cb   = (const float*)d_in[6];
  const float* rw   = (const float*)d_in[7];
  const float* rbias= (const float*)d_in[8];
  const float* lng  = (const float*)d_in[9];
  const float* lnb  = (const float*)d_in[10];
  const float* f1w  = (const float*)d_in[11];
  const float* f1b  = (const float*)d_in[12];
  const float* f2w  = (const float*)d_in[13];
  const float* f2b  = (const float*)d_in[14];
  float* out = (float*)d_out;
  char* w8 = (char*)d_ws;

  // Memory map (bytes), peak 162 MB (same as known-good R4):
  u16* xb    = (u16*)(w8 + 0);           // 16.78M (dead after qkv)
  u16* Wqb   = (u16*)(w8 + 16777216);    // 2M
  u16* Wkb   = (u16*)(w8 + 18874368);    // 2M
  u16* Wvb   = (u16*)(w8 + 20971520);    // 2M
  u16* rwb   = (u16*)(w8 + 23068672);    // 2M (until resgate)
  u16* f1wb  = (u16*)(w8 + 25165824);    // 1M (until fc1)
  u16* cwp   = (u16*)(w8 + 26214400);    // 1.5M (until conv)
  u16* qb    = (u16*)(w8 + 27787264);    // 16.78M (dead after scores)
  u16* kb    = (u16*)(w8 + 44564480);    // 16.78M (dead after scores)
  u16* vpad  = (u16*)(w8 + 61341696);    // 16.79M (dead after conv)
  u16* vT    = (u16*)(w8 + 78135296);    // 16.78M (dead after pv)
  float* att = (float*)(w8 + 94912512);  // 67.1M fp32 (dead after softmax)
  // Aliases (lifetime-checked):
  u16* attb  = (u16*)(w8 + 27787264);    // over qb+kb (softmax -> pv)
  u16* pvb   = (u16*)(w8 + 94912512);    // over att (pv -> conv)
  u16* buf1b = (u16*)(w8 + 27787264);    // over attb (conv -> resgate)
  u16* buf2  = (u16*)(w8 + 111689728);   // after pvb (resgate -> ln)
  u16* ln16  = (u16*)(w8 + 78135296);    // over vT (ln -> fc1)
  u16* h     = (u16*)(w8 + 61341696);    // over vpad (fc1 -> fc2)

  k_prep   <<<dim3(13832),     256, 0, stream>>>(x, Wq, Wk, Wv, rw, f1w, cw,
                                                 xb, Wqb, Wkb, Wvb, rwb, f1wb,
                                                 cwp, vpad);
  k_qkv    <<<dim3(64, 8, 3),  256, 0, stream>>>(xb, Wqb, Wkb, Wvb, qb, kb, vpad);
  k_vt     <<<dim3(32, 16, 4), 256, 0, stream>>>(vpad, vT);
  k_scores <<<dim3(16, 16, 4), 256, 0, stream>>>(qb, kb, rb, att);
  k_softmax<<<dim3(NSEQ, BSZ), 256, 0, stream>>>(att, attb);
  k_pv     <<<dim3(16, 8, 4),  256, 0, stream>>>(attb, vT, pvb);
  k_conv   <<<dim3(64, 8),     256, 0, stream>>>(vpad, cwp, cb, pvb, buf1b);
  k_resgate<<<dim3(64, 8),     256, 0, stream>>>(buf1b, rwb, rbias, x, buf2);
  k_ln     <<<dim3(BSZ * NSEQ),256, 0, stream>>>(buf2, lng, lnb, ln16);
  k_fc1    <<<dim3(64, 4),     256, 0, stream>>>(ln16, f1wb, f1b, h);
  k_fc2    <<<dim3(NSEQ),      256, 0, stream>>>(h, f2w, f2b, out);
}